// Round 3
// baseline (1962.251 us; speedup 1.0000x reference)
//
#include <hip/hip_runtime.h>
#include <math.h>

#define N_NODES 100000
#define N_EDGES 1600000
#define DIM     128
#define NCLS    64
#define ALPHA   0.1f

#define SCAN_B  98            // ceil(100000/1024)

// ================= CSR build (counting sort by dst) =================

__global__ void k_count(const int* __restrict__ dst, int* __restrict__ deg) {
    int e = blockIdx.x * blockDim.x + threadIdx.x;
    if (e < N_EDGES) atomicAdd(&deg[dst[e]], 1);
}

// phase 1: per-block exclusive scan of deg -> row_ptr (block-local), blocksum[b]
__global__ __launch_bounds__(1024) void k_scan1(const int* __restrict__ deg,
                                                int* __restrict__ row_ptr,
                                                int* __restrict__ blocksum) {
    __shared__ int s[1024];
    int t = threadIdx.x;
    int i = blockIdx.x * 1024 + t;
    int v = (i < N_NODES) ? deg[i] : 0;
    s[t] = v;
    __syncthreads();
    for (int off = 1; off < 1024; off <<= 1) {
        int u = (t >= off) ? s[t - off] : 0;
        __syncthreads();
        s[t] += u;
        __syncthreads();
    }
    if (i < N_NODES) row_ptr[i] = s[t] - v;          // exclusive within block
    if (t == 1023) blocksum[blockIdx.x] = s[1023];
}

// phase 2: single small block scans the 98 block sums (exclusive, in place)
__global__ __launch_bounds__(128) void k_scan2(int* __restrict__ blocksum) {
    __shared__ int s[128];
    int t = threadIdx.x;
    int v = (t < SCAN_B) ? blocksum[t] : 0;
    s[t] = v;
    __syncthreads();
    for (int off = 1; off < 128; off <<= 1) {
        int u = (t >= off) ? s[t - off] : 0;
        __syncthreads();
        s[t] += u;
        __syncthreads();
    }
    if (t < SCAN_B) blocksum[t] = s[t] - v;          // exclusive block offset
}

// phase 3: add block offset; emit row_ptr + cursor; row_ptr[N] = E (constant)
__global__ __launch_bounds__(1024) void k_scan3(int* __restrict__ row_ptr,
                                                int* __restrict__ cursor,
                                                const int* __restrict__ blocksum) {
    int t = threadIdx.x;
    int i = blockIdx.x * 1024 + t;
    if (i < N_NODES) {
        int rp = row_ptr[i] + blocksum[blockIdx.x];
        row_ptr[i] = rp;
        cursor[i] = rp;
    }
    if (i == 0) row_ptr[N_NODES] = N_EDGES;
}

// colw[pos] = (src, (1-ALPHA)*w) packed
__global__ void k_scatter(const int* __restrict__ src, const int* __restrict__ dst,
                          const float* __restrict__ ew, int* __restrict__ cursor,
                          int2* __restrict__ colw) {
    int e = blockIdx.x * blockDim.x + threadIdx.x;
    if (e >= N_EDGES) return;
    int d = dst[e];
    int pos = atomicAdd(&cursor[d], 1);
    colw[pos] = make_int2(src[e], __float_as_int((1.0f - ALPHA) * ew[e]));
}

// ================= input GEMM: h0 = relu(x @ W_in + b) =================
#define RPW 8
#define RPB 32

__global__ __launch_bounds__(256, 2) void k_in(
    const float* __restrict__ x, const float* __restrict__ W,
    const float* __restrict__ b, float* __restrict__ h0) {
    __shared__ float sW[DIM * DIM];
    __shared__ float srow[RPB][DIM];
    int tid = threadIdx.x;
    int wave = tid >> 6, lane = tid & 63;
    int w8 = wave * RPW;
    for (int i = tid; i < DIM * DIM / 4; i += 256)
        ((float4*)sW)[i] = ((const float4*)W)[i];
    __syncthreads();
    float2 bv = ((const float2*)b)[lane];

    for (int base = blockIdx.x * RPB; base < N_NODES; base += gridDim.x * RPB) {
        int r0 = base + w8;
        #pragma unroll
        for (int i = 0; i < RPW; i++) {
            int row = r0 + i;
            float2 v = (row < N_NODES) ? ((const float2*)(x + (size_t)row * DIM))[lane]
                                       : make_float2(0.f, 0.f);
            ((float2*)srow[w8 + i])[lane] = v;
        }
        float2 acc[RPW];
        #pragma unroll
        for (int i = 0; i < RPW; i++) acc[i] = make_float2(0.f, 0.f);
        #pragma unroll 4
        for (int k = 0; k < DIM; k++) {
            float2 wv = ((const float2*)(sW + k * DIM))[lane];
            #pragma unroll
            for (int i = 0; i < RPW; i++) {
                float xv = srow[w8 + i][k];
                acc[i].x += xv * wv.x;
                acc[i].y += xv * wv.y;
            }
        }
        #pragma unroll
        for (int i = 0; i < RPW; i++) {
            int row = r0 + i;
            if (row < N_NODES) {
                float ox = fmaxf(acc[i].x + bv.x, 0.f);
                float oy = fmaxf(acc[i].y + bv.y, 0.f);
                ((float2*)(h0 + (size_t)row * DIM))[lane] = make_float2(ox, oy);
            }
        }
    }
}

// ===== fused layer: gather support row (CSR) then GEMM, no hi buffer =====
// h = relu(theta*(support@W) + (1-theta)*support + hprev)
// support[i] = ALPHA*h0[i] + sum_e (1-ALPHA)*w_e*hprev[src_e]
__global__ __launch_bounds__(256, 2) void k_fused_layer(
    const int* __restrict__ row_ptr, const int2* __restrict__ colw,
    const float* __restrict__ hprev, const float* __restrict__ h0,
    const float* __restrict__ W, float* __restrict__ hout, float theta) {
    __shared__ float sW[DIM * DIM];
    __shared__ float srow[RPB][DIM];
    int tid = threadIdx.x;
    int wave = tid >> 6, lane = tid & 63;
    int w8 = wave * RPW;
    for (int i = tid; i < DIM * DIM / 4; i += 256)
        ((float4*)sW)[i] = ((const float4*)W)[i];
    __syncthreads();
    float omt = 1.f - theta;

    for (int base = blockIdx.x * RPB; base < N_NODES; base += gridDim.x * RPB) {
        int r0 = base + w8;
        float2 sv[RPW];
        // ---- gather phase: 8 nodes per wave, support row into regs + LDS ----
        #pragma unroll
        for (int i = 0; i < RPW; i++) {
            int node = r0 + i;
            float2 acc = make_float2(0.f, 0.f);
            if (node < N_NODES) {
                float2 z = ((const float2*)(h0 + (size_t)node * DIM))[lane];
                acc.x = ALPHA * z.x;
                acc.y = ALPHA * z.y;
                int beg = row_ptr[node], end = row_ptr[node + 1];
                int e = beg;
                for (; e + 1 < end; e += 2) {
                    int2 c0 = colw[e];
                    int2 c1 = colw[e + 1];
                    float2 v0 = ((const float2*)(hprev + (size_t)c0.x * DIM))[lane];
                    float2 v1 = ((const float2*)(hprev + (size_t)c1.x * DIM))[lane];
                    float w0 = __int_as_float(c0.y), w1 = __int_as_float(c1.y);
                    acc.x += w0 * v0.x + w1 * v1.x;
                    acc.y += w0 * v0.y + w1 * v1.y;
                }
                if (e < end) {
                    int2 c0 = colw[e];
                    float2 v0 = ((const float2*)(hprev + (size_t)c0.x * DIM))[lane];
                    float w0 = __int_as_float(c0.y);
                    acc.x += w0 * v0.x;
                    acc.y += w0 * v0.y;
                }
            }
            sv[i] = acc;
            ((float2*)srow[w8 + i])[lane] = acc;   // wave-private LDS slice
        }
        // ---- GEMM phase (same-wave LDS RAW; compiler inserts lgkmcnt wait) ----
        float2 macc[RPW];
        #pragma unroll
        for (int i = 0; i < RPW; i++) macc[i] = make_float2(0.f, 0.f);
        #pragma unroll 4
        for (int k = 0; k < DIM; k++) {
            float2 wv = ((const float2*)(sW + k * DIM))[lane];
            #pragma unroll
            for (int i = 0; i < RPW; i++) {
                float xv = srow[w8 + i][k];
                macc[i].x += xv * wv.x;
                macc[i].y += xv * wv.y;
            }
        }
        #pragma unroll
        for (int i = 0; i < RPW; i++) {
            int node = r0 + i;
            if (node < N_NODES) {
                float2 hp = ((const float2*)(hprev + (size_t)node * DIM))[lane];
                float ox = theta * macc[i].x + omt * sv[i].x + hp.x;
                float oy = theta * macc[i].y + omt * sv[i].y + hp.y;
                ((float2*)(hout + (size_t)node * DIM))[lane] =
                    make_float2(fmaxf(ox, 0.f), fmaxf(oy, 0.f));
            }
        }
    }
}

// ================= output: log_softmax(h @ W_out + b_out) =================
__global__ __launch_bounds__(256, 2) void k_out(
    const float* __restrict__ h, const float* __restrict__ Wo,
    const float* __restrict__ bo, float* __restrict__ out) {
    __shared__ float sW[DIM * NCLS];
    __shared__ float srow[4][DIM];
    int tid = threadIdx.x, wave = tid >> 6, lane = tid & 63;
    for (int i = tid; i < DIM * NCLS / 4; i += 256)
        ((float4*)sW)[i] = ((const float4*)Wo)[i];
    __syncthreads();
    int row = blockIdx.x * 4 + wave;
    if (row >= N_NODES) return;
    ((float2*)srow[wave])[lane] = ((const float2*)(h + (size_t)row * DIM))[lane];
    float acc = bo[lane];
    #pragma unroll 4
    for (int k = 0; k < DIM; k++)
        acc += srow[wave][k] * sW[k * NCLS + lane];
    float m = acc;
    #pragma unroll
    for (int off = 32; off; off >>= 1) m = fmaxf(m, __shfl_xor(m, off));
    float ex = __expf(acc - m);
    float s = ex;
    #pragma unroll
    for (int off = 32; off; off >>= 1) s += __shfl_xor(s, off);
    out[(size_t)row * NCLS + lane] = acc - m - logf(s);
}

extern "C" void kernel_launch(void* const* d_in, const int* in_sizes, int n_in,
                              void* d_out, int out_size, void* d_ws, size_t ws_size,
                              hipStream_t stream) {
    const float* x    = (const float*)d_in[0];
    const int*   esrc = (const int*)d_in[1];
    const int*   edst = (const int*)d_in[2];
    const float* ew   = (const float*)d_in[3];
    const float* w_in = (const float*)d_in[4];
    const float* b_in = (const float*)d_in[5];
    const float* gcnw = (const float*)d_in[6];   // [4,128,128]
    const float* wout = (const float*)d_in[7];
    const float* bout = (const float*)d_in[8];
    float* out = (float*)d_out;

    // workspace layout (4B units)
    float* ws = (float*)d_ws;
    float* h0   = ws;                                  // 12.8M floats
    float* hA   = h0 + (size_t)N_NODES * DIM;          // 12.8M
    float* hB   = hA + (size_t)N_NODES * DIM;          // 12.8M
    int2*  colw = (int2*)(hB + (size_t)N_NODES * DIM); // 1.6M int2
    int*   row_ptr  = (int*)(colw + N_EDGES);          // N+1 ints
    int*   cursor   = row_ptr + (N_NODES + 1);         // N ints
    int*   deg      = cursor + N_NODES;                // N ints
    int*   blocksum = deg + N_NODES;                   // SCAN_B ints

    const int EB = (N_EDGES + 255) / 256;
    const int GEMM_BLOCKS = 512;

    // ---- CSR build ----
    hipMemsetAsync(deg, 0, N_NODES * sizeof(int), stream);
    k_count<<<EB, 256, 0, stream>>>(edst, deg);
    k_scan1<<<SCAN_B, 1024, 0, stream>>>(deg, row_ptr, blocksum);
    k_scan2<<<1, 128, 0, stream>>>(blocksum);
    k_scan3<<<SCAN_B, 1024, 0, stream>>>(row_ptr, cursor, blocksum);
    k_scatter<<<EB, 256, 0, stream>>>(esrc, edst, ew, cursor, colw);

    // h0 = relu(x @ w_in + b_in)
    k_in<<<GEMM_BLOCKS, 256, 0, stream>>>(x, w_in, b_in, h0);

    const float* hprev = h0;
    float* bufs[2] = {hA, hB};
    for (int l = 0; l < 4; l++) {
        float theta = logf(0.5f / (float)(l + 2) + 1.0f);
        float* hnew = bufs[l & 1];
        k_fused_layer<<<GEMM_BLOCKS, 256, 0, stream>>>(
            row_ptr, colw, hprev, h0, gcnw + (size_t)l * DIM * DIM, hnew, theta);
        hprev = hnew;
    }

    // out = log_softmax(h @ w_out + b_out)
    k_out<<<(N_NODES + 3) / 4, 256, 0, stream>>>(hprev, wout, bout, out);
}

// Round 4
// 1273.261 us; speedup vs baseline: 1.5411x; 1.5411x over previous
//
#include <hip/hip_runtime.h>
#include <math.h>

#define N_NODES 100000
#define N_EDGES 1600000
#define DIM     128
#define NCLS    64
#define ALPHA   0.1f

#define SCAN_B  98            // ceil(100000/1024)

// ================= CSR build (counting sort by dst) =================

__global__ void k_count(const int* __restrict__ dst, int* __restrict__ deg) {
    int e = blockIdx.x * blockDim.x + threadIdx.x;
    if (e < N_EDGES) atomicAdd(&deg[dst[e]], 1);
}

// phase 1: per-block exclusive scan of deg -> row_ptr (block-local), blocksum[b]
__global__ __launch_bounds__(1024) void k_scan1(const int* __restrict__ deg,
                                                int* __restrict__ row_ptr,
                                                int* __restrict__ blocksum) {
    __shared__ int s[1024];
    int t = threadIdx.x;
    int i = blockIdx.x * 1024 + t;
    int v = (i < N_NODES) ? deg[i] : 0;
    s[t] = v;
    __syncthreads();
    for (int off = 1; off < 1024; off <<= 1) {
        int u = (t >= off) ? s[t - off] : 0;
        __syncthreads();
        s[t] += u;
        __syncthreads();
    }
    if (i < N_NODES) row_ptr[i] = s[t] - v;          // exclusive within block
    if (t == 1023) blocksum[blockIdx.x] = s[1023];
}

// phase 2: single small block scans the 98 block sums (exclusive, in place)
__global__ __launch_bounds__(128) void k_scan2(int* __restrict__ blocksum) {
    __shared__ int s[128];
    int t = threadIdx.x;
    int v = (t < SCAN_B) ? blocksum[t] : 0;
    s[t] = v;
    __syncthreads();
    for (int off = 1; off < 128; off <<= 1) {
        int u = (t >= off) ? s[t - off] : 0;
        __syncthreads();
        s[t] += u;
        __syncthreads();
    }
    if (t < SCAN_B) blocksum[t] = s[t] - v;          // exclusive block offset
}

// phase 3: add block offset; emit row_ptr + cursor; row_ptr[N] = E (constant)
__global__ __launch_bounds__(1024) void k_scan3(int* __restrict__ row_ptr,
                                                int* __restrict__ cursor,
                                                const int* __restrict__ blocksum) {
    int t = threadIdx.x;
    int i = blockIdx.x * 1024 + t;
    if (i < N_NODES) {
        int rp = row_ptr[i] + blocksum[blockIdx.x];
        row_ptr[i] = rp;
        cursor[i] = rp;
    }
    if (i == 0) row_ptr[N_NODES] = N_EDGES;
}

// colw[pos] = (src, (1-ALPHA)*w) packed
__global__ void k_scatter(const int* __restrict__ src, const int* __restrict__ dst,
                          const float* __restrict__ ew, int* __restrict__ cursor,
                          int2* __restrict__ colw) {
    int e = blockIdx.x * blockDim.x + threadIdx.x;
    if (e >= N_EDGES) return;
    int d = dst[e];
    int pos = atomicAdd(&cursor[d], 1);
    colw[pos] = make_int2(src[e], __float_as_int((1.0f - ALPHA) * ew[e]));
}

// ===== SpMM gather: out[i] = ALPHA*h0[i] + sum_e w*h[src]  (no atomics) =====
// one wave per dst node; lane owns 2 dims (float2). No LDS -> full occupancy;
// 4-edge unroll keeps 4 independent 512B row loads in flight per wave.
__global__ __launch_bounds__(256, 8) void k_spmm_csr(
    const int* __restrict__ row_ptr, const int2* __restrict__ colw,
    const float* __restrict__ h, const float* __restrict__ h0,
    float* __restrict__ out) {
    int node = blockIdx.x * 4 + (threadIdx.x >> 6);
    if (node >= N_NODES) return;
    int lane = threadIdx.x & 63;
    int beg = row_ptr[node], end = row_ptr[node + 1];

    float2 z = ((const float2*)(h0 + (size_t)node * DIM))[lane];
    float2 acc = make_float2(ALPHA * z.x, ALPHA * z.y);

    int e = beg;
    for (; e + 3 < end; e += 4) {
        int2 c0 = colw[e];
        int2 c1 = colw[e + 1];
        int2 c2 = colw[e + 2];
        int2 c3 = colw[e + 3];
        float2 v0 = ((const float2*)(h + (size_t)c0.x * DIM))[lane];
        float2 v1 = ((const float2*)(h + (size_t)c1.x * DIM))[lane];
        float2 v2 = ((const float2*)(h + (size_t)c2.x * DIM))[lane];
        float2 v3 = ((const float2*)(h + (size_t)c3.x * DIM))[lane];
        float w0 = __int_as_float(c0.y), w1 = __int_as_float(c1.y);
        float w2 = __int_as_float(c2.y), w3 = __int_as_float(c3.y);
        acc.x += w0 * v0.x + w1 * v1.x + w2 * v2.x + w3 * v3.x;
        acc.y += w0 * v0.y + w1 * v1.y + w2 * v2.y + w3 * v3.y;
    }
    for (; e < end; e++) {
        int2 c0 = colw[e];
        float2 v0 = ((const float2*)(h + (size_t)c0.x * DIM))[lane];
        float w0 = __int_as_float(c0.y);
        acc.x += w0 * v0.x;
        acc.y += w0 * v0.y;
    }
    ((float2*)(out + (size_t)node * DIM))[lane] = acc;
}

// ================= input GEMM: h0 = relu(x @ W_in + b) =================
#define RPW 8
#define RPB 32

__global__ __launch_bounds__(256, 2) void k_in(
    const float* __restrict__ x, const float* __restrict__ W,
    const float* __restrict__ b, float* __restrict__ h0) {
    __shared__ float sW[DIM * DIM];
    __shared__ float srow[RPB][DIM];
    int tid = threadIdx.x;
    int wave = tid >> 6, lane = tid & 63;
    int w8 = wave * RPW;
    for (int i = tid; i < DIM * DIM / 4; i += 256)
        ((float4*)sW)[i] = ((const float4*)W)[i];
    __syncthreads();
    float2 bv = ((const float2*)b)[lane];

    for (int base = blockIdx.x * RPB; base < N_NODES; base += gridDim.x * RPB) {
        int r0 = base + w8;
        #pragma unroll
        for (int i = 0; i < RPW; i++) {
            int row = r0 + i;
            float2 v = (row < N_NODES) ? ((const float2*)(x + (size_t)row * DIM))[lane]
                                       : make_float2(0.f, 0.f);
            ((float2*)srow[w8 + i])[lane] = v;
        }
        float2 acc[RPW];
        #pragma unroll
        for (int i = 0; i < RPW; i++) acc[i] = make_float2(0.f, 0.f);
        #pragma unroll 4
        for (int k = 0; k < DIM; k++) {
            float2 wv = ((const float2*)(sW + k * DIM))[lane];
            #pragma unroll
            for (int i = 0; i < RPW; i++) {
                float xv = srow[w8 + i][k];
                acc[i].x += xv * wv.x;
                acc[i].y += xv * wv.y;
            }
        }
        #pragma unroll
        for (int i = 0; i < RPW; i++) {
            int row = r0 + i;
            if (row < N_NODES) {
                float ox = fmaxf(acc[i].x + bv.x, 0.f);
                float oy = fmaxf(acc[i].y + bv.y, 0.f);
                ((float2*)(h0 + (size_t)row * DIM))[lane] = make_float2(ox, oy);
            }
        }
    }
}

// ========== layer GEMM: h = relu(theta*(s@W) + (1-theta)*s + hprev) ==========
__global__ __launch_bounds__(256, 2) void k_layer(
    const float* __restrict__ s_in, const float* __restrict__ hprev,
    const float* __restrict__ W, float* __restrict__ hout, float theta) {
    __shared__ float sW[DIM * DIM];
    __shared__ float srow[RPB][DIM];
    int tid = threadIdx.x;
    int wave = tid >> 6, lane = tid & 63;
    int w8 = wave * RPW;
    for (int i = tid; i < DIM * DIM / 4; i += 256)
        ((float4*)sW)[i] = ((const float4*)W)[i];
    __syncthreads();
    float omt = 1.f - theta;

    for (int base = blockIdx.x * RPB; base < N_NODES; base += gridDim.x * RPB) {
        int r0 = base + w8;
        float2 sv[RPW];
        #pragma unroll
        for (int i = 0; i < RPW; i++) {
            int row = r0 + i;
            float2 v = (row < N_NODES) ? ((const float2*)(s_in + (size_t)row * DIM))[lane]
                                       : make_float2(0.f, 0.f);
            sv[i] = v;
            ((float2*)srow[w8 + i])[lane] = v;
        }
        float2 acc[RPW];
        #pragma unroll
        for (int i = 0; i < RPW; i++) acc[i] = make_float2(0.f, 0.f);
        #pragma unroll 4
        for (int k = 0; k < DIM; k++) {
            float2 wv = ((const float2*)(sW + k * DIM))[lane];
            #pragma unroll
            for (int i = 0; i < RPW; i++) {
                float xv = srow[w8 + i][k];
                acc[i].x += xv * wv.x;
                acc[i].y += xv * wv.y;
            }
        }
        #pragma unroll
        for (int i = 0; i < RPW; i++) {
            int row = r0 + i;
            if (row < N_NODES) {
                float2 hp = ((const float2*)(hprev + (size_t)row * DIM))[lane];
                float ox = theta * acc[i].x + omt * sv[i].x + hp.x;
                float oy = theta * acc[i].y + omt * sv[i].y + hp.y;
                ((float2*)(hout + (size_t)row * DIM))[lane] =
                    make_float2(fmaxf(ox, 0.f), fmaxf(oy, 0.f));
            }
        }
    }
}

// ================= output: log_softmax(h @ W_out + b_out) =================
__global__ __launch_bounds__(256, 2) void k_out(
    const float* __restrict__ h, const float* __restrict__ Wo,
    const float* __restrict__ bo, float* __restrict__ out) {
    __shared__ float sW[DIM * NCLS];
    __shared__ float srow[4][DIM];
    int tid = threadIdx.x, wave = tid >> 6, lane = tid & 63;
    for (int i = tid; i < DIM * NCLS / 4; i += 256)
        ((float4*)sW)[i] = ((const float4*)Wo)[i];
    __syncthreads();
    int row = blockIdx.x * 4 + wave;
    if (row >= N_NODES) return;
    ((float2*)srow[wave])[lane] = ((const float2*)(h + (size_t)row * DIM))[lane];
    float acc = bo[lane];
    #pragma unroll 4
    for (int k = 0; k < DIM; k++)
        acc += srow[wave][k] * sW[k * NCLS + lane];
    float m = acc;
    #pragma unroll
    for (int off = 32; off; off >>= 1) m = fmaxf(m, __shfl_xor(m, off));
    float ex = __expf(acc - m);
    float s = ex;
    #pragma unroll
    for (int off = 32; off; off >>= 1) s += __shfl_xor(s, off);
    out[(size_t)row * NCLS + lane] = acc - m - logf(s);
}

extern "C" void kernel_launch(void* const* d_in, const int* in_sizes, int n_in,
                              void* d_out, int out_size, void* d_ws, size_t ws_size,
                              hipStream_t stream) {
    const float* x    = (const float*)d_in[0];
    const int*   esrc = (const int*)d_in[1];
    const int*   edst = (const int*)d_in[2];
    const float* ew   = (const float*)d_in[3];
    const float* w_in = (const float*)d_in[4];
    const float* b_in = (const float*)d_in[5];
    const float* gcnw = (const float*)d_in[6];   // [4,128,128]
    const float* wout = (const float*)d_in[7];
    const float* bout = (const float*)d_in[8];
    float* out = (float*)d_out;

    // workspace layout (4B units)
    float* ws = (float*)d_ws;
    float* h0   = ws;                                  // 12.8M floats
    float* hA   = h0 + (size_t)N_NODES * DIM;          // 12.8M
    float* hB   = hA + (size_t)N_NODES * DIM;          // 12.8M
    float* hi   = hB + (size_t)N_NODES * DIM;          // 12.8M
    int2*  colw = (int2*)(hi + (size_t)N_NODES * DIM); // 1.6M int2
    int*   row_ptr  = (int*)(colw + N_EDGES);          // N+1 ints
    int*   cursor   = row_ptr + (N_NODES + 1);         // N ints
    int*   deg      = cursor + N_NODES;                // N ints
    int*   blocksum = deg + N_NODES;                   // SCAN_B ints

    const int EB = (N_EDGES + 255) / 256;
    const int GEMM_BLOCKS = 512;

    // ---- CSR build ----
    hipMemsetAsync(deg, 0, N_NODES * sizeof(int), stream);
    k_count<<<EB, 256, 0, stream>>>(edst, deg);
    k_scan1<<<SCAN_B, 1024, 0, stream>>>(deg, row_ptr, blocksum);
    k_scan2<<<1, 128, 0, stream>>>(blocksum);
    k_scan3<<<SCAN_B, 1024, 0, stream>>>(row_ptr, cursor, blocksum);
    k_scatter<<<EB, 256, 0, stream>>>(esrc, edst, ew, cursor, colw);

    // h0 = relu(x @ w_in + b_in)
    k_in<<<GEMM_BLOCKS, 256, 0, stream>>>(x, w_in, b_in, h0);

    const float* hprev = h0;
    float* bufs[2] = {hA, hB};
    for (int l = 0; l < 4; l++) {
        float theta = logf(0.5f / (float)(l + 2) + 1.0f);
        // hi = ALPHA*h0 + gather  (separate kernel: needs max occupancy)
        k_spmm_csr<<<(N_NODES + 3) / 4, 256, 0, stream>>>(row_ptr, colw, hprev, h0, hi);
        // h = relu(theta*(hi@W_l) + (1-theta)*hi + hprev)  (LDS-heavy GEMM)
        float* hnew = bufs[l & 1];
        k_layer<<<GEMM_BLOCKS, 256, 0, stream>>>(hi, hprev, gcnw + (size_t)l * DIM * DIM,
                                                 hnew, theta);
        hprev = hnew;
    }

    // out = log_softmax(h @ w_out + b_out)
    k_out<<<(N_NODES + 3) / 4, 256, 0, stream>>>(hprev, wout, bout, out);
}

// Round 5
// 1103.514 us; speedup vs baseline: 1.7782x; 1.1538x over previous
//
#include <hip/hip_runtime.h>
#include <math.h>

#define N_NODES 100000
#define N_EDGES 1600000
#define DIM     128
#define NCLS    64
#define ALPHA   0.1f

#define SCAN_B  98            // ceil(100000/1024)
#define NF      ((size_t)N_NODES * DIM)

// ---- bf16 helpers (storage only; all math fp32) ----
__device__ __forceinline__ float bf2f(unsigned short u) {
    return __uint_as_float((unsigned int)u << 16);
}
__device__ __forceinline__ float2 bf2f2(ushort2 u) {
    return make_float2(bf2f(u.x), bf2f(u.y));
}
__device__ __forceinline__ unsigned short f2bf(float x) {
    unsigned int u = __float_as_uint(x);
    u += 0x7FFFu + ((u >> 16) & 1u);          // round-to-nearest-even
    return (unsigned short)(u >> 16);
}
__device__ __forceinline__ ushort2 f2bf2(float2 v) {
    return make_ushort2(f2bf(v.x), f2bf(v.y));
}

// ================= CSR build (counting sort by dst) =================

__global__ void k_count(const int* __restrict__ dst, int* __restrict__ deg) {
    int e = blockIdx.x * blockDim.x + threadIdx.x;
    if (e < N_EDGES) atomicAdd(&deg[dst[e]], 1);
}

__global__ __launch_bounds__(1024) void k_scan1(const int* __restrict__ deg,
                                                int* __restrict__ row_ptr,
                                                int* __restrict__ blocksum) {
    __shared__ int s[1024];
    int t = threadIdx.x;
    int i = blockIdx.x * 1024 + t;
    int v = (i < N_NODES) ? deg[i] : 0;
    s[t] = v;
    __syncthreads();
    for (int off = 1; off < 1024; off <<= 1) {
        int u = (t >= off) ? s[t - off] : 0;
        __syncthreads();
        s[t] += u;
        __syncthreads();
    }
    if (i < N_NODES) row_ptr[i] = s[t] - v;
    if (t == 1023) blocksum[blockIdx.x] = s[1023];
}

__global__ __launch_bounds__(128) void k_scan2(int* __restrict__ blocksum) {
    __shared__ int s[128];
    int t = threadIdx.x;
    int v = (t < SCAN_B) ? blocksum[t] : 0;
    s[t] = v;
    __syncthreads();
    for (int off = 1; off < 128; off <<= 1) {
        int u = (t >= off) ? s[t - off] : 0;
        __syncthreads();
        s[t] += u;
        __syncthreads();
    }
    if (t < SCAN_B) blocksum[t] = s[t] - v;
}

__global__ __launch_bounds__(1024) void k_scan3(int* __restrict__ row_ptr,
                                                int* __restrict__ cursor,
                                                const int* __restrict__ blocksum) {
    int t = threadIdx.x;
    int i = blockIdx.x * 1024 + t;
    if (i < N_NODES) {
        int rp = row_ptr[i] + blocksum[blockIdx.x];
        row_ptr[i] = rp;
        cursor[i] = rp;
    }
    if (i == 0) row_ptr[N_NODES] = N_EDGES;
}

__global__ void k_scatter(const int* __restrict__ src, const int* __restrict__ dst,
                          const float* __restrict__ ew, int* __restrict__ cursor,
                          int2* __restrict__ colw) {
    int e = blockIdx.x * blockDim.x + threadIdx.x;
    if (e >= N_EDGES) return;
    int d = dst[e];
    int pos = atomicAdd(&cursor[d], 1);
    colw[pos] = make_int2(src[e], __float_as_int((1.0f - ALPHA) * ew[e]));
}

// ===== SpMM gather (bf16 rows): hi[i] = ALPHA*h0[i] + sum_e w*h[src] =====
// one wave per dst node; lane owns 2 dims (ushort2 = 4B); 4-edge unroll.
__global__ __launch_bounds__(256, 8) void k_spmm_csr(
    const int* __restrict__ row_ptr, const int2* __restrict__ colw,
    const unsigned short* __restrict__ h, const unsigned short* __restrict__ h0,
    unsigned short* __restrict__ out) {
    int node = blockIdx.x * 4 + (threadIdx.x >> 6);
    if (node >= N_NODES) return;
    int lane = threadIdx.x & 63;
    int beg = row_ptr[node], end = row_ptr[node + 1];

    float2 z = bf2f2(((const ushort2*)(h0 + (size_t)node * DIM))[lane]);
    float2 acc = make_float2(ALPHA * z.x, ALPHA * z.y);

    int e = beg;
    for (; e + 3 < end; e += 4) {
        int2 c0 = colw[e];
        int2 c1 = colw[e + 1];
        int2 c2 = colw[e + 2];
        int2 c3 = colw[e + 3];
        float2 v0 = bf2f2(((const ushort2*)(h + (size_t)c0.x * DIM))[lane]);
        float2 v1 = bf2f2(((const ushort2*)(h + (size_t)c1.x * DIM))[lane]);
        float2 v2 = bf2f2(((const ushort2*)(h + (size_t)c2.x * DIM))[lane]);
        float2 v3 = bf2f2(((const ushort2*)(h + (size_t)c3.x * DIM))[lane]);
        float w0 = __int_as_float(c0.y), w1 = __int_as_float(c1.y);
        float w2 = __int_as_float(c2.y), w3 = __int_as_float(c3.y);
        acc.x += w0 * v0.x + w1 * v1.x + w2 * v2.x + w3 * v3.x;
        acc.y += w0 * v0.y + w1 * v1.y + w2 * v2.y + w3 * v3.y;
    }
    for (; e < end; e++) {
        int2 c0 = colw[e];
        float2 v0 = bf2f2(((const ushort2*)(h + (size_t)c0.x * DIM))[lane]);
        float w0 = __int_as_float(c0.y);
        acc.x += w0 * v0.x;
        acc.y += w0 * v0.y;
    }
    ((ushort2*)(out + (size_t)node * DIM))[lane] = f2bf2(acc);
}

// ================= input GEMM: h0 = relu(x @ W_in + b)  (bf16 out) =========
#define RPW 8
#define RPB 32

__global__ __launch_bounds__(256, 2) void k_in(
    const float* __restrict__ x, const float* __restrict__ W,
    const float* __restrict__ b, unsigned short* __restrict__ h0) {
    __shared__ float sW[DIM * DIM];
    __shared__ float srow[RPB][DIM];
    int tid = threadIdx.x;
    int wave = tid >> 6, lane = tid & 63;
    int w8 = wave * RPW;
    for (int i = tid; i < DIM * DIM / 4; i += 256)
        ((float4*)sW)[i] = ((const float4*)W)[i];
    __syncthreads();
    float2 bv = ((const float2*)b)[lane];

    for (int base = blockIdx.x * RPB; base < N_NODES; base += gridDim.x * RPB) {
        int r0 = base + w8;
        #pragma unroll
        for (int i = 0; i < RPW; i++) {
            int row = r0 + i;
            float2 v = (row < N_NODES) ? ((const float2*)(x + (size_t)row * DIM))[lane]
                                       : make_float2(0.f, 0.f);
            ((float2*)srow[w8 + i])[lane] = v;
        }
        float2 acc[RPW];
        #pragma unroll
        for (int i = 0; i < RPW; i++) acc[i] = make_float2(0.f, 0.f);
        // chunked: 4 k's per iter, ds_read_b128 for srow
        for (int k4 = 0; k4 < DIM / 4; k4++) {
            int k = k4 * 4;
            float2 wv0 = ((const float2*)(sW + (k + 0) * DIM))[lane];
            float2 wv1 = ((const float2*)(sW + (k + 1) * DIM))[lane];
            float2 wv2 = ((const float2*)(sW + (k + 2) * DIM))[lane];
            float2 wv3 = ((const float2*)(sW + (k + 3) * DIM))[lane];
            #pragma unroll
            for (int i = 0; i < RPW; i++) {
                float4 s4 = ((const float4*)srow[w8 + i])[k4];
                acc[i].x += s4.x * wv0.x + s4.y * wv1.x + s4.z * wv2.x + s4.w * wv3.x;
                acc[i].y += s4.x * wv0.y + s4.y * wv1.y + s4.z * wv2.y + s4.w * wv3.y;
            }
        }
        #pragma unroll
        for (int i = 0; i < RPW; i++) {
            int row = r0 + i;
            if (row < N_NODES) {
                float ox = fmaxf(acc[i].x + bv.x, 0.f);
                float oy = fmaxf(acc[i].y + bv.y, 0.f);
                ((ushort2*)(h0 + (size_t)row * DIM))[lane] = f2bf2(make_float2(ox, oy));
            }
        }
    }
}

// ===== layer GEMM (bf16 in/out): h = relu(theta*(s@W) + (1-theta)*s + hprev) =====
__global__ __launch_bounds__(256, 2) void k_layer(
    const unsigned short* __restrict__ s_in, const unsigned short* __restrict__ hprev,
    const float* __restrict__ W, unsigned short* __restrict__ hout, float theta) {
    __shared__ float sW[DIM * DIM];
    __shared__ float srow[RPB][DIM];
    int tid = threadIdx.x;
    int wave = tid >> 6, lane = tid & 63;
    int w8 = wave * RPW;
    for (int i = tid; i < DIM * DIM / 4; i += 256)
        ((float4*)sW)[i] = ((const float4*)W)[i];
    __syncthreads();
    float omt = 1.f - theta;

    for (int base = blockIdx.x * RPB; base < N_NODES; base += gridDim.x * RPB) {
        int r0 = base + w8;
        float2 sv[RPW];
        #pragma unroll
        for (int i = 0; i < RPW; i++) {
            int row = r0 + i;
            float2 v = (row < N_NODES)
                ? bf2f2(((const ushort2*)(s_in + (size_t)row * DIM))[lane])
                : make_float2(0.f, 0.f);
            sv[i] = v;
            ((float2*)srow[w8 + i])[lane] = v;
        }
        float2 acc[RPW];
        #pragma unroll
        for (int i = 0; i < RPW; i++) acc[i] = make_float2(0.f, 0.f);
        for (int k4 = 0; k4 < DIM / 4; k4++) {
            int k = k4 * 4;
            float2 wv0 = ((const float2*)(sW + (k + 0) * DIM))[lane];
            float2 wv1 = ((const float2*)(sW + (k + 1) * DIM))[lane];
            float2 wv2 = ((const float2*)(sW + (k + 2) * DIM))[lane];
            float2 wv3 = ((const float2*)(sW + (k + 3) * DIM))[lane];
            #pragma unroll
            for (int i = 0; i < RPW; i++) {
                float4 s4 = ((const float4*)srow[w8 + i])[k4];
                acc[i].x += s4.x * wv0.x + s4.y * wv1.x + s4.z * wv2.x + s4.w * wv3.x;
                acc[i].y += s4.x * wv0.y + s4.y * wv1.y + s4.z * wv2.y + s4.w * wv3.y;
            }
        }
        #pragma unroll
        for (int i = 0; i < RPW; i++) {
            int row = r0 + i;
            if (row < N_NODES) {
                float2 hp = bf2f2(((const ushort2*)(hprev + (size_t)row * DIM))[lane]);
                float ox = theta * acc[i].x + omt * sv[i].x + hp.x;
                float oy = theta * acc[i].y + omt * sv[i].y + hp.y;
                ((ushort2*)(hout + (size_t)row * DIM))[lane] =
                    f2bf2(make_float2(fmaxf(ox, 0.f), fmaxf(oy, 0.f)));
            }
        }
    }
}

// ======= output: log_softmax(h @ W_out + b_out)  (bf16 in, fp32 out) =======
__global__ __launch_bounds__(256, 2) void k_out(
    const unsigned short* __restrict__ h, const float* __restrict__ Wo,
    const float* __restrict__ bo, float* __restrict__ out) {
    __shared__ float sW[DIM * NCLS];
    __shared__ float srow[4][DIM];
    int tid = threadIdx.x, wave = tid >> 6, lane = tid & 63;
    for (int i = tid; i < DIM * NCLS / 4; i += 256)
        ((float4*)sW)[i] = ((const float4*)Wo)[i];
    __syncthreads();
    int row = blockIdx.x * 4 + wave;
    if (row >= N_NODES) return;
    ((float2*)srow[wave])[lane] = bf2f2(((const ushort2*)(h + (size_t)row * DIM))[lane]);
    float acc = bo[lane];
    for (int k4 = 0; k4 < DIM / 4; k4++) {
        float4 s4 = ((const float4*)srow[wave])[k4];
        int k = k4 * 4;
        acc += s4.x * sW[(k + 0) * NCLS + lane] + s4.y * sW[(k + 1) * NCLS + lane]
             + s4.z * sW[(k + 2) * NCLS + lane] + s4.w * sW[(k + 3) * NCLS + lane];
    }
    float m = acc;
    #pragma unroll
    for (int off = 32; off; off >>= 1) m = fmaxf(m, __shfl_xor(m, off));
    float ex = __expf(acc - m);
    float s = ex;
    #pragma unroll
    for (int off = 32; off; off >>= 1) s += __shfl_xor(s, off);
    out[(size_t)row * NCLS + lane] = acc - m - logf(s);
}

extern "C" void kernel_launch(void* const* d_in, const int* in_sizes, int n_in,
                              void* d_out, int out_size, void* d_ws, size_t ws_size,
                              hipStream_t stream) {
    const float* x    = (const float*)d_in[0];
    const int*   esrc = (const int*)d_in[1];
    const int*   edst = (const int*)d_in[2];
    const float* ew   = (const float*)d_in[3];
    const float* w_in = (const float*)d_in[4];
    const float* b_in = (const float*)d_in[5];
    const float* gcnw = (const float*)d_in[6];   // [4,128,128]
    const float* wout = (const float*)d_in[7];
    const float* bout = (const float*)d_in[8];
    float* out = (float*)d_out;

    // workspace layout: 4 bf16 feature buffers then CSR arrays
    unsigned short* h0 = (unsigned short*)d_ws;        // NF ushorts (25.6 MB)
    unsigned short* hA = h0 + NF;
    unsigned short* hB = hA + NF;
    unsigned short* hi = hB + NF;
    int2* colw = (int2*)(hi + NF);                     // 1.6M int2 (8B-aligned)
    int*  row_ptr  = (int*)(colw + N_EDGES);
    int*  cursor   = row_ptr + (N_NODES + 1);
    int*  deg      = cursor + N_NODES;
    int*  blocksum = deg + N_NODES;

    const int EB = (N_EDGES + 255) / 256;
    const int GEMM_BLOCKS = 512;

    // ---- CSR build ----
    hipMemsetAsync(deg, 0, N_NODES * sizeof(int), stream);
    k_count<<<EB, 256, 0, stream>>>(edst, deg);
    k_scan1<<<SCAN_B, 1024, 0, stream>>>(deg, row_ptr, blocksum);
    k_scan2<<<1, 128, 0, stream>>>(blocksum);
    k_scan3<<<SCAN_B, 1024, 0, stream>>>(row_ptr, cursor, blocksum);
    k_scatter<<<EB, 256, 0, stream>>>(esrc, edst, ew, cursor, colw);

    // h0 = relu(x @ w_in + b_in)
    k_in<<<GEMM_BLOCKS, 256, 0, stream>>>(x, w_in, b_in, h0);

    const unsigned short* hprev = h0;
    unsigned short* bufs[2] = {hA, hB};
    for (int l = 0; l < 4; l++) {
        float theta = logf(0.5f / (float)(l + 2) + 1.0f);
        k_spmm_csr<<<(N_NODES + 3) / 4, 256, 0, stream>>>(row_ptr, colw, hprev, h0, hi);
        unsigned short* hnew = bufs[l & 1];
        k_layer<<<GEMM_BLOCKS, 256, 0, stream>>>(hi, hprev, gcnw + (size_t)l * DIM * DIM,
                                                 hnew, theta);
        hprev = hnew;
    }

    // out = log_softmax(h @ w_out + b_out)
    k_out<<<(N_NODES + 3) / 4, 256, 0, stream>>>(hprev, wout, bout, out);
}

// Round 6
// 749.557 us; speedup vs baseline: 2.6179x; 1.4722x over previous
//
#include <hip/hip_runtime.h>
#include <math.h>

#define N_NODES 100000
#define N_EDGES 1600000
#define DIM     128
#define NCLS    64
#define ALPHA   0.1f

#define SCAN_B  98            // ceil(100000/1024)
#define NF      ((size_t)N_NODES * DIM)
#define STRIPES (N_NODES / 16)    // 6250 exact

typedef __attribute__((ext_vector_type(8))) short  bf16x8;
typedef __attribute__((ext_vector_type(4))) float  f32x4;

// ---- bf16 helpers (storage only; all math fp32) ----
__device__ __forceinline__ float bf2f(unsigned short u) {
    return __uint_as_float((unsigned int)u << 16);
}
__device__ __forceinline__ float2 bf2f2(ushort2 u) {
    return make_float2(bf2f(u.x), bf2f(u.y));
}
__device__ __forceinline__ unsigned short f2bf(float x) {
    unsigned int u = __float_as_uint(x);
    u += 0x7FFFu + ((u >> 16) & 1u);          // round-to-nearest-even
    return (unsigned short)(u >> 16);
}
__device__ __forceinline__ ushort2 f2bf2(float2 v) {
    return make_ushort2(f2bf(v.x), f2bf(v.y));
}

// ================= CSR build (counting sort by dst) =================

__global__ void k_count(const int* __restrict__ dst, int* __restrict__ deg) {
    int e = blockIdx.x * blockDim.x + threadIdx.x;
    if (e < N_EDGES) atomicAdd(&deg[dst[e]], 1);
}

__global__ __launch_bounds__(1024) void k_scan1(const int* __restrict__ deg,
                                                int* __restrict__ row_ptr,
                                                int* __restrict__ blocksum) {
    __shared__ int s[1024];
    int t = threadIdx.x;
    int i = blockIdx.x * 1024 + t;
    int v = (i < N_NODES) ? deg[i] : 0;
    s[t] = v;
    __syncthreads();
    for (int off = 1; off < 1024; off <<= 1) {
        int u = (t >= off) ? s[t - off] : 0;
        __syncthreads();
        s[t] += u;
        __syncthreads();
    }
    if (i < N_NODES) row_ptr[i] = s[t] - v;
    if (t == 1023) blocksum[blockIdx.x] = s[1023];
}

__global__ __launch_bounds__(128) void k_scan2(int* __restrict__ blocksum) {
    __shared__ int s[128];
    int t = threadIdx.x;
    int v = (t < SCAN_B) ? blocksum[t] : 0;
    s[t] = v;
    __syncthreads();
    for (int off = 1; off < 128; off <<= 1) {
        int u = (t >= off) ? s[t - off] : 0;
        __syncthreads();
        s[t] += u;
        __syncthreads();
    }
    if (t < SCAN_B) blocksum[t] = s[t] - v;
}

__global__ __launch_bounds__(1024) void k_scan3(int* __restrict__ row_ptr,
                                                int* __restrict__ cursor,
                                                const int* __restrict__ blocksum) {
    int t = threadIdx.x;
    int i = blockIdx.x * 1024 + t;
    if (i < N_NODES) {
        int rp = row_ptr[i] + blocksum[blockIdx.x];
        row_ptr[i] = rp;
        cursor[i] = rp;
    }
    if (i == 0) row_ptr[N_NODES] = N_EDGES;
}

__global__ void k_scatter(const int* __restrict__ src, const int* __restrict__ dst,
                          const float* __restrict__ ew, int* __restrict__ cursor,
                          int2* __restrict__ colw) {
    int e = blockIdx.x * blockDim.x + threadIdx.x;
    if (e >= N_EDGES) return;
    int d = dst[e];
    int pos = atomicAdd(&cursor[d], 1);
    colw[pos] = make_int2(src[e], __float_as_int((1.0f - ALPHA) * ew[e]));
}

// ===== weight pack: fp32 W[k][n] -> bf16 B-fragment order =====
// idx = ((nt*4 + ch)*64 + lane)*8 + j ; value = W[ch*32 + (lane>>4)*8 + j][nt*16 + (lane&15)]
// layers (nt:0..7) at wp[l*16384]; w_out (nt:0..3) at wp[65536].
__global__ void k_prepw(const float* __restrict__ gcnw, const float* __restrict__ wout,
                        unsigned short* __restrict__ wp) {
    int tid = blockIdx.x * 256 + threadIdx.x;
    if (tid < 65536) {
        int l = tid >> 14;
        int r = tid & 16383;
        int j = r & 7, lane = (r >> 3) & 63, ch = (r >> 9) & 3, nt = r >> 11;
        int n = nt * 16 + (lane & 15);
        int k = ch * 32 + (lane >> 4) * 8 + j;
        wp[tid] = f2bf(gcnw[l * 16384 + k * 128 + n]);
    } else if (tid < 73728) {
        int r = tid - 65536;
        int j = r & 7, lane = (r >> 3) & 63, ch = (r >> 9) & 3, nt = r >> 11; // nt 0..3
        int n = nt * 16 + (lane & 15);
        int k = ch * 32 + (lane >> 4) * 8 + j;
        wp[tid] = f2bf(wout[k * 64 + n]);
    }
}

// ===== SpMM gather (bf16 rows): hi[i] = ALPHA*h0[i] + sum_e w*h[src] =====
__global__ __launch_bounds__(256, 8) void k_spmm_csr(
    const int* __restrict__ row_ptr, const int2* __restrict__ colw,
    const unsigned short* __restrict__ h, const unsigned short* __restrict__ h0,
    unsigned short* __restrict__ out) {
    int node = blockIdx.x * 4 + (threadIdx.x >> 6);
    if (node >= N_NODES) return;
    int lane = threadIdx.x & 63;
    int beg = row_ptr[node], end = row_ptr[node + 1];

    float2 z = bf2f2(((const ushort2*)(h0 + (size_t)node * DIM))[lane]);
    float2 acc = make_float2(ALPHA * z.x, ALPHA * z.y);

    int e = beg;
    for (; e + 3 < end; e += 4) {
        int2 c0 = colw[e];
        int2 c1 = colw[e + 1];
        int2 c2 = colw[e + 2];
        int2 c3 = colw[e + 3];
        float2 v0 = bf2f2(((const ushort2*)(h + (size_t)c0.x * DIM))[lane]);
        float2 v1 = bf2f2(((const ushort2*)(h + (size_t)c1.x * DIM))[lane]);
        float2 v2 = bf2f2(((const ushort2*)(h + (size_t)c2.x * DIM))[lane]);
        float2 v3 = bf2f2(((const ushort2*)(h + (size_t)c3.x * DIM))[lane]);
        float w0 = __int_as_float(c0.y), w1 = __int_as_float(c1.y);
        float w2 = __int_as_float(c2.y), w3 = __int_as_float(c3.y);
        acc.x += w0 * v0.x + w1 * v1.x + w2 * v2.x + w3 * v3.x;
        acc.y += w0 * v0.y + w1 * v1.y + w2 * v2.y + w3 * v3.y;
    }
    for (; e < end; e++) {
        int2 c0 = colw[e];
        float2 v0 = bf2f2(((const ushort2*)(h + (size_t)c0.x * DIM))[lane]);
        float w0 = __int_as_float(c0.y);
        acc.x += w0 * v0.x;
        acc.y += w0 * v0.y;
    }
    ((ushort2*)(out + (size_t)node * DIM))[lane] = f2bf2(acc);
}

// ================= input GEMM: h0 = relu(x @ W_in + b)  (fp32 VALU) =========
#define RPW 8
#define RPB 32

__global__ __launch_bounds__(256, 2) void k_in(
    const float* __restrict__ x, const float* __restrict__ W,
    const float* __restrict__ b, unsigned short* __restrict__ h0) {
    __shared__ float sW[DIM * DIM];
    __shared__ float srow[RPB][DIM];
    int tid = threadIdx.x;
    int wave = tid >> 6, lane = tid & 63;
    int w8 = wave * RPW;
    for (int i = tid; i < DIM * DIM / 4; i += 256)
        ((float4*)sW)[i] = ((const float4*)W)[i];
    __syncthreads();
    float2 bv = ((const float2*)b)[lane];

    for (int base = blockIdx.x * RPB; base < N_NODES; base += gridDim.x * RPB) {
        int r0 = base + w8;
        #pragma unroll
        for (int i = 0; i < RPW; i++) {
            int row = r0 + i;
            float2 v = (row < N_NODES) ? ((const float2*)(x + (size_t)row * DIM))[lane]
                                       : make_float2(0.f, 0.f);
            ((float2*)srow[w8 + i])[lane] = v;
        }
        float2 acc[RPW];
        #pragma unroll
        for (int i = 0; i < RPW; i++) acc[i] = make_float2(0.f, 0.f);
        for (int k4 = 0; k4 < DIM / 4; k4++) {
            int k = k4 * 4;
            float2 wv0 = ((const float2*)(sW + (k + 0) * DIM))[lane];
            float2 wv1 = ((const float2*)(sW + (k + 1) * DIM))[lane];
            float2 wv2 = ((const float2*)(sW + (k + 2) * DIM))[lane];
            float2 wv3 = ((const float2*)(sW + (k + 3) * DIM))[lane];
            #pragma unroll
            for (int i = 0; i < RPW; i++) {
                float4 s4 = ((const float4*)srow[w8 + i])[k4];
                acc[i].x += s4.x * wv0.x + s4.y * wv1.x + s4.z * wv2.x + s4.w * wv3.x;
                acc[i].y += s4.x * wv0.y + s4.y * wv1.y + s4.z * wv2.y + s4.w * wv3.y;
            }
        }
        #pragma unroll
        for (int i = 0; i < RPW; i++) {
            int row = r0 + i;
            if (row < N_NODES) {
                float ox = fmaxf(acc[i].x + bv.x, 0.f);
                float oy = fmaxf(acc[i].y + bv.y, 0.f);
                ((ushort2*)(h0 + (size_t)row * DIM))[lane] = f2bf2(make_float2(ox, oy));
            }
        }
    }
}

// ===== MFMA layer GEMM: h = relu(theta*(s@W) + (1-theta)*s + hprev) =====
// one wave per 16-row stripe; 8 n-tiles x 4 k-chunks of 16x16x32 bf16 MFMA.
// A-frag: lane holds A[r0+(lane&15)][ch*32 + (lane>>4)*8 + j] -> 16B contig load.
// B-frag: pre-packed by k_prepw -> 16B/lane coalesced, L1/L2-hot.
// C/D: col = lane&15, row = (lane>>4)*4 + reg.
__global__ __launch_bounds__(256) void k_layer_mfma(
    const unsigned short* __restrict__ s_in, const unsigned short* __restrict__ hprev,
    const unsigned short* __restrict__ wp, unsigned short* __restrict__ hout,
    float theta) {
    int wave = threadIdx.x >> 6, lane = threadIdx.x & 63;
    int stripe = blockIdx.x * 4 + wave;
    if (stripe >= STRIPES) return;
    int r0 = stripe * 16;
    int m = lane & 15, q = lane >> 4;
    float omt = 1.f - theta;

    f32x4 acc[8];
    #pragma unroll
    for (int nt = 0; nt < 8; nt++) acc[nt] = (f32x4){0.f, 0.f, 0.f, 0.f};

    const unsigned short* arow = s_in + (size_t)(r0 + m) * DIM + q * 8;
    #pragma unroll
    for (int ch = 0; ch < 4; ch++) {
        bf16x8 a = *(const bf16x8*)(arow + ch * 32);
        #pragma unroll
        for (int nt = 0; nt < 8; nt++) {
            bf16x8 b = *(const bf16x8*)(wp + (((nt * 4 + ch) * 64 + lane) << 3));
            acc[nt] = __builtin_amdgcn_mfma_f32_16x16x32_bf16(a, b, acc[nt], 0, 0, 0);
        }
    }

    #pragma unroll
    for (int nt = 0; nt < 8; nt++) {
        int col = nt * 16 + m;
        #pragma unroll
        for (int r = 0; r < 4; r++) {
            int row = r0 + q * 4 + r;
            size_t idx = (size_t)row * DIM + col;
            float sup = bf2f(s_in[idx]);
            float hp  = bf2f(hprev[idx]);
            float o = theta * acc[nt][r] + omt * sup + hp;
            hout[idx] = f2bf(fmaxf(o, 0.f));
        }
    }
}

// ===== MFMA output GEMM + log_softmax: out = log_softmax(h @ W_out + b) =====
// 4 n-tiles x 4 k-chunks; per-row softmax via in-lane (over nt) + shfl over m.
__global__ __launch_bounds__(256) void k_out_mfma(
    const unsigned short* __restrict__ h, const unsigned short* __restrict__ wp,
    const float* __restrict__ bo, float* __restrict__ out) {
    int wave = threadIdx.x >> 6, lane = threadIdx.x & 63;
    int stripe = blockIdx.x * 4 + wave;
    if (stripe >= STRIPES) return;
    int r0 = stripe * 16;
    int m = lane & 15, q = lane >> 4;

    f32x4 acc[4];
    #pragma unroll
    for (int nt = 0; nt < 4; nt++) acc[nt] = (f32x4){0.f, 0.f, 0.f, 0.f};

    const unsigned short* arow = h + (size_t)(r0 + m) * DIM + q * 8;
    #pragma unroll
    for (int ch = 0; ch < 4; ch++) {
        bf16x8 a = *(const bf16x8*)(arow + ch * 32);
        #pragma unroll
        for (int nt = 0; nt < 4; nt++) {
            bf16x8 b = *(const bf16x8*)(wp + (((nt * 4 + ch) * 64 + lane) << 3));
            acc[nt] = __builtin_amdgcn_mfma_f32_16x16x32_bf16(a, b, acc[nt], 0, 0, 0);
        }
    }

    // logits v[nt][r] = acc + bias ; row = r0+4q+r, col = nt*16+m
    float v[4][4];
    #pragma unroll
    for (int nt = 0; nt < 4; nt++) {
        float bias = bo[nt * 16 + m];
        #pragma unroll
        for (int r = 0; r < 4; r++) v[nt][r] = acc[nt][r] + bias;
    }
    // per-row max: over nt in-lane, then over the 16-lane m-group
    #pragma unroll
    for (int r = 0; r < 4; r++) {
        float mx = fmaxf(fmaxf(v[0][r], v[1][r]), fmaxf(v[2][r], v[3][r]));
        #pragma unroll
        for (int off = 1; off < 16; off <<= 1) mx = fmaxf(mx, __shfl_xor(mx, off));
        float s = 0.f;
        #pragma unroll
        for (int nt = 0; nt < 4; nt++) s += __expf(v[nt][r] - mx);
        #pragma unroll
        for (int off = 1; off < 16; off <<= 1) s += __shfl_xor(s, off);
        float lse = mx + logf(s);
        int row = r0 + q * 4 + r;
        #pragma unroll
        for (int nt = 0; nt < 4; nt++)
            out[(size_t)row * NCLS + nt * 16 + m] = v[nt][r] - lse;
    }
}

extern "C" void kernel_launch(void* const* d_in, const int* in_sizes, int n_in,
                              void* d_out, int out_size, void* d_ws, size_t ws_size,
                              hipStream_t stream) {
    const float* x    = (const float*)d_in[0];
    const int*   esrc = (const int*)d_in[1];
    const int*   edst = (const int*)d_in[2];
    const float* ew   = (const float*)d_in[3];
    const float* w_in = (const float*)d_in[4];
    const float* b_in = (const float*)d_in[5];
    const float* gcnw = (const float*)d_in[6];   // [4,128,128]
    const float* wout = (const float*)d_in[7];
    const float* bout = (const float*)d_in[8];
    float* out = (float*)d_out;

    // workspace layout: 4 bf16 feature buffers, packed weights, CSR arrays
    unsigned short* h0 = (unsigned short*)d_ws;        // NF ushorts (25.6 MB)
    unsigned short* hA = h0 + NF;
    unsigned short* hB = hA + NF;
    unsigned short* hi = hB + NF;
    unsigned short* wp = hi + NF;                      // 73728 ushorts (packed W)
    int2* colw = (int2*)(wp + 73728);                  // 1.6M int2 (8B-aligned)
    int*  row_ptr  = (int*)(colw + N_EDGES);
    int*  cursor   = row_ptr + (N_NODES + 1);
    int*  deg      = cursor + N_NODES;
    int*  blocksum = deg + N_NODES;

    const int EB = (N_EDGES + 255) / 256;
    const int GEMM_BLOCKS = 512;
    const int MFMA_BLOCKS = (STRIPES + 3) / 4;

    // ---- weight pack (independent) ----
    k_prepw<<<(73728 + 255) / 256, 256, 0, stream>>>(gcnw, wout, wp);

    // ---- CSR build ----
    hipMemsetAsync(deg, 0, N_NODES * sizeof(int), stream);
    k_count<<<EB, 256, 0, stream>>>(edst, deg);
    k_scan1<<<SCAN_B, 1024, 0, stream>>>(deg, row_ptr, blocksum);
    k_scan2<<<1, 128, 0, stream>>>(blocksum);
    k_scan3<<<SCAN_B, 1024, 0, stream>>>(row_ptr, cursor, blocksum);
    k_scatter<<<EB, 256, 0, stream>>>(esrc, edst, ew, cursor, colw);

    // h0 = relu(x @ w_in + b_in)
    k_in<<<GEMM_BLOCKS, 256, 0, stream>>>(x, w_in, b_in, h0);

    const unsigned short* hprev = h0;
    unsigned short* bufs[2] = {hA, hB};
    for (int l = 0; l < 4; l++) {
        float theta = logf(0.5f / (float)(l + 2) + 1.0f);
        k_spmm_csr<<<(N_NODES + 3) / 4, 256, 0, stream>>>(row_ptr, colw, hprev, h0, hi);
        unsigned short* hnew = bufs[l & 1];
        k_layer_mfma<<<MFMA_BLOCKS, 256, 0, stream>>>(hi, hprev, wp + (size_t)l * 16384,
                                                      hnew, theta);
        hprev = hnew;
    }

    // out = log_softmax(h @ w_out + b_out)
    k_out_mfma<<<MFMA_BLOCKS, 256, 0, stream>>>(hprev, wp + 65536, bout, out);
}

// Round 7
// 648.597 us; speedup vs baseline: 3.0254x; 1.1557x over previous
//
#include <hip/hip_runtime.h>
#include <math.h>

#define N_NODES 100000
#define N_EDGES 1600000
#define DIM     128
#define NCLS    64
#define ALPHA   0.1f

#define SCAN_B  98                 // ceil(100000/1024)
#define NB      391                // ceil(100000/256) dst-buckets of 256 nodes
#define NF      ((size_t)N_NODES * DIM)
#define STRIPES (N_NODES / 16)     // 6250 exact
#define CHUNK   16384              // edges per partition block

typedef __attribute__((ext_vector_type(8))) short  bf16x8;
typedef __attribute__((ext_vector_type(4))) float  f32x4;

// ---- bf16 helpers (storage only; accumulation fp32) ----
__device__ __forceinline__ float bf2f(unsigned short u) {
    return __uint_as_float((unsigned int)u << 16);
}
__device__ __forceinline__ float2 bf2f2(ushort2 u) {
    return make_float2(bf2f(u.x), bf2f(u.y));
}
__device__ __forceinline__ unsigned short f2bf(float x) {
    unsigned int u = __float_as_uint(x);
    u += 0x7FFFu + ((u >> 16) & 1u);          // round-to-nearest-even
    return (unsigned short)(u >> 16);
}
__device__ __forceinline__ ushort2 f2bf2(float2 v) {
    return make_ushort2(f2bf(v.x), f2bf(v.y));
}

// ================= bucketed CSR build =================
// bucket = dst >> 8 (256 nodes/bucket). ebuf entry: x = src | dst_local<<17, y = 0.9*w.

__global__ __launch_bounds__(256) void k_hist(const int* __restrict__ dst,
                                              int* __restrict__ bucket_cnt) {
    __shared__ int hist[NB];
    int t = threadIdx.x;
    for (int b = t; b < NB; b += 256) hist[b] = 0;
    __syncthreads();
    int base = blockIdx.x * CHUNK;
    int end = min(base + CHUNK, N_EDGES);
    for (int i = base + t; i < end; i += 256)
        atomicAdd(&hist[dst[i] >> 8], 1);
    __syncthreads();
    for (int b = t; b < NB; b += 256)
        if (hist[b]) atomicAdd(&bucket_cnt[b], hist[b]);
}

__global__ __launch_bounds__(512) void k_scanb(const int* __restrict__ bucket_cnt,
                                               int* __restrict__ bucket_base,
                                               int* __restrict__ bucket_cursor) {
    __shared__ int s[512];
    int t = threadIdx.x;
    int v = (t < NB) ? bucket_cnt[t] : 0;
    s[t] = v;
    __syncthreads();
    for (int off = 1; off < 512; off <<= 1) {
        int u = (t >= off) ? s[t - off] : 0;
        __syncthreads();
        s[t] += u;
        __syncthreads();
    }
    if (t < NB) {
        int base = s[t] - v;
        bucket_base[t] = base;
        bucket_cursor[t] = base;
    }
    if (t == 0) bucket_base[NB] = N_EDGES;
}

__global__ __launch_bounds__(256) void k_part(const int* __restrict__ src,
                                              const int* __restrict__ dst,
                                              const float* __restrict__ ew,
                                              int* __restrict__ bucket_cursor,
                                              int2* __restrict__ ebuf) {
    __shared__ int lhist[NB], gbase[NB];
    int t = threadIdx.x;
    for (int b = t; b < NB; b += 256) lhist[b] = 0;
    __syncthreads();
    int base = blockIdx.x * CHUNK;
    int end = min(base + CHUNK, N_EDGES);
    for (int i = base + t; i < end; i += 256)
        atomicAdd(&lhist[dst[i] >> 8], 1);
    __syncthreads();
    for (int b = t; b < NB; b += 256) {
        int c = lhist[b];
        gbase[b] = c ? atomicAdd(&bucket_cursor[b], c) : 0;
        lhist[b] = 0;
    }
    __syncthreads();
    for (int i = base + t; i < end; i += 256) {
        int d = dst[i];
        int b = d >> 8;
        int r = atomicAdd(&lhist[b], 1);
        ebuf[gbase[b] + r] = make_int2(src[i] | ((d & 255) << 17),
                                       __float_as_int((1.0f - ALPHA) * ew[i]));
    }
}

// per-bucket degree via LDS counters (no global atomics)
__global__ __launch_bounds__(256) void k_deg(const int2* __restrict__ ebuf,
                                             const int* __restrict__ bucket_base,
                                             int* __restrict__ deg) {
    __shared__ int cnt[256];
    int t = threadIdx.x, b = blockIdx.x;
    cnt[t] = 0;
    __syncthreads();
    int beg = bucket_base[b], end = bucket_base[b + 1];
    for (int i = beg + t; i < end; i += 256)
        atomicAdd(&cnt[ebuf[i].x >> 17], 1);
    __syncthreads();
    int node = b * 256 + t;
    if (node < N_NODES) deg[node] = cnt[t];
}

__global__ __launch_bounds__(1024) void k_scan1(const int* __restrict__ deg,
                                                int* __restrict__ row_ptr,
                                                int* __restrict__ blocksum) {
    __shared__ int s[1024];
    int t = threadIdx.x;
    int i = blockIdx.x * 1024 + t;
    int v = (i < N_NODES) ? deg[i] : 0;
    s[t] = v;
    __syncthreads();
    for (int off = 1; off < 1024; off <<= 1) {
        int u = (t >= off) ? s[t - off] : 0;
        __syncthreads();
        s[t] += u;
        __syncthreads();
    }
    if (i < N_NODES) row_ptr[i] = s[t] - v;
    if (t == 1023) blocksum[blockIdx.x] = s[1023];
}

__global__ __launch_bounds__(128) void k_scan2(int* __restrict__ blocksum) {
    __shared__ int s[128];
    int t = threadIdx.x;
    int v = (t < SCAN_B) ? blocksum[t] : 0;
    s[t] = v;
    __syncthreads();
    for (int off = 1; off < 128; off <<= 1) {
        int u = (t >= off) ? s[t - off] : 0;
        __syncthreads();
        s[t] += u;
        __syncthreads();
    }
    if (t < SCAN_B) blocksum[t] = s[t] - v;
}

__global__ __launch_bounds__(1024) void k_scan3(int* __restrict__ row_ptr,
                                                const int* __restrict__ blocksum) {
    int t = threadIdx.x;
    int i = blockIdx.x * 1024 + t;
    if (i < N_NODES) row_ptr[i] += blocksum[blockIdx.x];
    if (i == 0) row_ptr[N_NODES] = N_EDGES;
}

// per-bucket counting-sort scatter; LDS cursors, colw writes confined to ~32KB
__global__ __launch_bounds__(256) void k_scatter2(const int2* __restrict__ ebuf,
                                                  const int* __restrict__ bucket_base,
                                                  const int* __restrict__ row_ptr,
                                                  int2* __restrict__ colw) {
    __shared__ int lcur[256];
    int t = threadIdx.x, b = blockIdx.x;
    int node = b * 256 + t;
    lcur[t] = (node < N_NODES) ? row_ptr[node] : 0;
    __syncthreads();
    int beg = bucket_base[b], end = bucket_base[b + 1];
    for (int i = beg + t; i < end; i += 256) {
        int2 e = ebuf[i];
        int pos = atomicAdd(&lcur[e.x >> 17], 1);
        colw[pos] = make_int2(e.x & 0x1FFFF, e.y);
    }
}

// ===== weight pack: fp32 -> bf16 B-fragment order =====
// frag idx = ((nt*4 + ch)*64 + lane)*8 + j ;
// value = W[ch*32 + (lane>>4)*8 + j][nt*16 + (lane&15)]
// layers at wp[l*16384] (l=0..3), w_out at wp[65536] (nt 0..3), w_in at wp[73728].
__global__ void k_prepw(const float* __restrict__ gcnw, const float* __restrict__ wout,
                        const float* __restrict__ win, unsigned short* __restrict__ wp) {
    int tid = blockIdx.x * 256 + threadIdx.x;
    if (tid < 65536) {
        int l = tid >> 14;
        int r = tid & 16383;
        int j = r & 7, lane = (r >> 3) & 63, ch = (r >> 9) & 3, nt = r >> 11;
        int n = nt * 16 + (lane & 15);
        int k = ch * 32 + (lane >> 4) * 8 + j;
        wp[tid] = f2bf(gcnw[l * 16384 + k * 128 + n]);
    } else if (tid < 73728) {
        int r = tid - 65536;
        int j = r & 7, lane = (r >> 3) & 63, ch = (r >> 9) & 3, nt = r >> 11; // nt 0..3
        int n = nt * 16 + (lane & 15);
        int k = ch * 32 + (lane >> 4) * 8 + j;
        wp[tid] = f2bf(wout[k * 64 + n]);
    } else if (tid < 90112) {
        int r = tid - 73728;
        int j = r & 7, lane = (r >> 3) & 63, ch = (r >> 9) & 3, nt = r >> 11; // nt 0..7
        int n = nt * 16 + (lane & 15);
        int k = ch * 32 + (lane >> 4) * 8 + j;
        wp[tid] = f2bf(win[k * 128 + n]);
    }
}

// ===== SpMM gather (bf16 rows): hi[i] = ALPHA*h0[i] + sum_e w*h[src] =====
__global__ __launch_bounds__(256, 8) void k_spmm_csr(
    const int* __restrict__ row_ptr, const int2* __restrict__ colw,
    const unsigned short* __restrict__ h, const unsigned short* __restrict__ h0,
    unsigned short* __restrict__ out) {
    int node = blockIdx.x * 4 + (threadIdx.x >> 6);
    if (node >= N_NODES) return;
    int lane = threadIdx.x & 63;
    int beg = row_ptr[node], end = row_ptr[node + 1];

    float2 z = bf2f2(((const ushort2*)(h0 + (size_t)node * DIM))[lane]);
    float2 acc = make_float2(ALPHA * z.x, ALPHA * z.y);

    int e = beg;
    for (; e + 3 < end; e += 4) {
        int2 c0 = colw[e];
        int2 c1 = colw[e + 1];
        int2 c2 = colw[e + 2];
        int2 c3 = colw[e + 3];
        float2 v0 = bf2f2(((const ushort2*)(h + (size_t)c0.x * DIM))[lane]);
        float2 v1 = bf2f2(((const ushort2*)(h + (size_t)c1.x * DIM))[lane]);
        float2 v2 = bf2f2(((const ushort2*)(h + (size_t)c2.x * DIM))[lane]);
        float2 v3 = bf2f2(((const ushort2*)(h + (size_t)c3.x * DIM))[lane]);
        float w0 = __int_as_float(c0.y), w1 = __int_as_float(c1.y);
        float w2 = __int_as_float(c2.y), w3 = __int_as_float(c3.y);
        acc.x += w0 * v0.x + w1 * v1.x + w2 * v2.x + w3 * v3.x;
        acc.y += w0 * v0.y + w1 * v1.y + w2 * v2.y + w3 * v3.y;
    }
    for (; e < end; e++) {
        int2 c0 = colw[e];
        float2 v0 = bf2f2(((const ushort2*)(h + (size_t)c0.x * DIM))[lane]);
        float w0 = __int_as_float(c0.y);
        acc.x += w0 * v0.x;
        acc.y += w0 * v0.y;
    }
    ((ushort2*)(out + (size_t)node * DIM))[lane] = f2bf2(acc);
}

// ===== MFMA input GEMM: h0 = relu(x @ W_in + b)  (x fp32 -> bf16 in-reg) =====
__global__ __launch_bounds__(256) void k_in_mfma(
    const float* __restrict__ x, const unsigned short* __restrict__ wp,
    const float* __restrict__ b_in, unsigned short* __restrict__ h0) {
    int wave = threadIdx.x >> 6, lane = threadIdx.x & 63;
    int stripe = blockIdx.x * 4 + wave;
    if (stripe >= STRIPES) return;
    int r0 = stripe * 16;
    int m = lane & 15, q = lane >> 4;

    f32x4 acc[8];
    #pragma unroll
    for (int nt = 0; nt < 8; nt++) acc[nt] = (f32x4){0.f, 0.f, 0.f, 0.f};

    const float* xr = x + (size_t)(r0 + m) * DIM + q * 8;
    #pragma unroll
    for (int ch = 0; ch < 4; ch++) {
        float4 a0 = *(const float4*)(xr + ch * 32);
        float4 a1 = *(const float4*)(xr + ch * 32 + 4);
        bf16x8 a;
        a[0] = (short)f2bf(a0.x); a[1] = (short)f2bf(a0.y);
        a[2] = (short)f2bf(a0.z); a[3] = (short)f2bf(a0.w);
        a[4] = (short)f2bf(a1.x); a[5] = (short)f2bf(a1.y);
        a[6] = (short)f2bf(a1.z); a[7] = (short)f2bf(a1.w);
        #pragma unroll
        for (int nt = 0; nt < 8; nt++) {
            bf16x8 b = *(const bf16x8*)(wp + (((nt * 4 + ch) * 64 + lane) << 3));
            acc[nt] = __builtin_amdgcn_mfma_f32_16x16x32_bf16(a, b, acc[nt], 0, 0, 0);
        }
    }

    #pragma unroll
    for (int nt = 0; nt < 8; nt++) {
        int col = nt * 16 + m;
        float bias = b_in[col];
        #pragma unroll
        for (int r = 0; r < 4; r++) {
            int row = r0 + q * 4 + r;
            h0[(size_t)row * DIM + col] = f2bf(fmaxf(acc[nt][r] + bias, 0.f));
        }
    }
}

// ===== MFMA layer GEMM: h = relu(theta*(s@W) + (1-theta)*s + hprev) =====
__global__ __launch_bounds__(256) void k_layer_mfma(
    const unsigned short* __restrict__ s_in, const unsigned short* __restrict__ hprev,
    const unsigned short* __restrict__ wp, unsigned short* __restrict__ hout,
    float theta) {
    int wave = threadIdx.x >> 6, lane = threadIdx.x & 63;
    int stripe = blockIdx.x * 4 + wave;
    if (stripe >= STRIPES) return;
    int r0 = stripe * 16;
    int m = lane & 15, q = lane >> 4;
    float omt = 1.f - theta;

    f32x4 acc[8];
    #pragma unroll
    for (int nt = 0; nt < 8; nt++) acc[nt] = (f32x4){0.f, 0.f, 0.f, 0.f};

    const unsigned short* arow = s_in + (size_t)(r0 + m) * DIM + q * 8;
    #pragma unroll
    for (int ch = 0; ch < 4; ch++) {
        bf16x8 a = *(const bf16x8*)(arow + ch * 32);
        #pragma unroll
        for (int nt = 0; nt < 8; nt++) {
            bf16x8 b = *(const bf16x8*)(wp + (((nt * 4 + ch) * 64 + lane) << 3));
            acc[nt] = __builtin_amdgcn_mfma_f32_16x16x32_bf16(a, b, acc[nt], 0, 0, 0);
        }
    }

    #pragma unroll
    for (int nt = 0; nt < 8; nt++) {
        int col = nt * 16 + m;
        #pragma unroll
        for (int r = 0; r < 4; r++) {
            int row = r0 + q * 4 + r;
            size_t idx = (size_t)row * DIM + col;
            float sup = bf2f(s_in[idx]);
            float hp  = bf2f(hprev[idx]);
            float o = theta * acc[nt][r] + omt * sup + hp;
            hout[idx] = f2bf(fmaxf(o, 0.f));
        }
    }
}

// ===== MFMA output GEMM + log_softmax =====
__global__ __launch_bounds__(256) void k_out_mfma(
    const unsigned short* __restrict__ h, const unsigned short* __restrict__ wp,
    const float* __restrict__ bo, float* __restrict__ out) {
    int wave = threadIdx.x >> 6, lane = threadIdx.x & 63;
    int stripe = blockIdx.x * 4 + wave;
    if (stripe >= STRIPES) return;
    int r0 = stripe * 16;
    int m = lane & 15, q = lane >> 4;

    f32x4 acc[4];
    #pragma unroll
    for (int nt = 0; nt < 4; nt++) acc[nt] = (f32x4){0.f, 0.f, 0.f, 0.f};

    const unsigned short* arow = h + (size_t)(r0 + m) * DIM + q * 8;
    #pragma unroll
    for (int ch = 0; ch < 4; ch++) {
        bf16x8 a = *(const bf16x8*)(arow + ch * 32);
        #pragma unroll
        for (int nt = 0; nt < 4; nt++) {
            bf16x8 b = *(const bf16x8*)(wp + (((nt * 4 + ch) * 64 + lane) << 3));
            acc[nt] = __builtin_amdgcn_mfma_f32_16x16x32_bf16(a, b, acc[nt], 0, 0, 0);
        }
    }

    float v[4][4];
    #pragma unroll
    for (int nt = 0; nt < 4; nt++) {
        float bias = bo[nt * 16 + m];
        #pragma unroll
        for (int r = 0; r < 4; r++) v[nt][r] = acc[nt][r] + bias;
    }
    #pragma unroll
    for (int r = 0; r < 4; r++) {
        float mx = fmaxf(fmaxf(v[0][r], v[1][r]), fmaxf(v[2][r], v[3][r]));
        #pragma unroll
        for (int off = 1; off < 16; off <<= 1) mx = fmaxf(mx, __shfl_xor(mx, off));
        float s = 0.f;
        #pragma unroll
        for (int nt = 0; nt < 4; nt++) s += __expf(v[nt][r] - mx);
        #pragma unroll
        for (int off = 1; off < 16; off <<= 1) s += __shfl_xor(s, off);
        float lse = mx + logf(s);
        int row = r0 + q * 4 + r;
        #pragma unroll
        for (int nt = 0; nt < 4; nt++)
            out[(size_t)row * NCLS + nt * 16 + m] = v[nt][r] - lse;
    }
}

extern "C" void kernel_launch(void* const* d_in, const int* in_sizes, int n_in,
                              void* d_out, int out_size, void* d_ws, size_t ws_size,
                              hipStream_t stream) {
    const float* x    = (const float*)d_in[0];
    const int*   esrc = (const int*)d_in[1];
    const int*   edst = (const int*)d_in[2];
    const float* ew   = (const float*)d_in[3];
    const float* w_in = (const float*)d_in[4];
    const float* b_in = (const float*)d_in[5];
    const float* gcnw = (const float*)d_in[6];   // [4,128,128]
    const float* wout = (const float*)d_in[7];
    const float* bout = (const float*)d_in[8];
    float* out = (float*)d_out;

    // workspace layout
    unsigned short* h0 = (unsigned short*)d_ws;        // NF ushorts each
    unsigned short* hA = h0 + NF;
    unsigned short* hB = hA + NF;
    unsigned short* hi = hB + NF;
    unsigned short* wp = hi + NF;                      // 90112 ushorts packed W
    int2* colw = (int2*)(wp + 90112);                  // E int2
    int2* ebuf = colw + N_EDGES;                       // E int2 (bucket-grouped)
    int*  row_ptr       = (int*)(ebuf + N_EDGES);      // N+1
    int*  deg           = row_ptr + (N_NODES + 1);     // N
    int*  blocksum      = deg + N_NODES;               // SCAN_B
    int*  bucket_cnt    = blocksum + SCAN_B;           // NB
    int*  bucket_base   = bucket_cnt + NB;             // NB+1
    int*  bucket_cursor = bucket_base + (NB + 1);      // NB

    const int PART_B = (N_EDGES + CHUNK - 1) / CHUNK;  // 98
    const int MFMA_BLOCKS = (STRIPES + 3) / 4;

    // ---- weight pack ----
    k_prepw<<<(90112 + 255) / 256, 256, 0, stream>>>(gcnw, wout, w_in, wp);

    // ---- bucketed CSR build ----
    hipMemsetAsync(bucket_cnt, 0, NB * sizeof(int), stream);
    k_hist<<<PART_B, 256, 0, stream>>>(edst, bucket_cnt);
    k_scanb<<<1, 512, 0, stream>>>(bucket_cnt, bucket_base, bucket_cursor);
    k_part<<<PART_B, 256, 0, stream>>>(esrc, edst, ew, bucket_cursor, ebuf);
    k_deg<<<NB, 256, 0, stream>>>(ebuf, bucket_base, deg);
    k_scan1<<<SCAN_B, 1024, 0, stream>>>(deg, row_ptr, blocksum);
    k_scan2<<<1, 128, 0, stream>>>(blocksum);
    k_scan3<<<SCAN_B, 1024, 0, stream>>>(row_ptr, blocksum);
    k_scatter2<<<NB, 256, 0, stream>>>(ebuf, bucket_base, row_ptr, colw);

    // h0 = relu(x @ w_in + b_in)
    k_in_mfma<<<MFMA_BLOCKS, 256, 0, stream>>>(x, wp + 73728, b_in, h0);

    const unsigned short* hprev = h0;
    unsigned short* bufs[2] = {hA, hB};
    for (int l = 0; l < 4; l++) {
        float theta = logf(0.5f / (float)(l + 2) + 1.0f);
        k_spmm_csr<<<(N_NODES + 3) / 4, 256, 0, stream>>>(row_ptr, colw, hprev, h0, hi);
        unsigned short* hnew = bufs[l & 1];
        k_layer_mfma<<<MFMA_BLOCKS, 256, 0, stream>>>(hi, hprev, wp + (size_t)l * 16384,
                                                      hnew, theta);
        hprev = hnew;
    }

    // out = log_softmax(h @ w_out + b_out)
    k_out_mfma<<<MFMA_BLOCKS, 256, 0, stream>>>(hprev, wp + 65536, bout, out);
}

// Round 8
// 632.377 us; speedup vs baseline: 3.1030x; 1.0256x over previous
//
#include <hip/hip_runtime.h>
#include <math.h>

#define N_NODES 100000
#define N_EDGES 1600000
#define DIM     128
#define NCLS    64
#define ALPHA   0.1f

#define SCAN_B  98                 // ceil(100000/1024)
#define NB      391                // ceil(100000/256) dst-buckets of 256 nodes
#define NF      ((size_t)N_NODES * DIM)
#define STRIPES (N_NODES / 16)     // 6250 exact
#define CHUNK   2048               // edges per partition block (R7: 16384 -> 3.7% occ)

typedef __attribute__((ext_vector_type(8))) short  bf16x8;
typedef __attribute__((ext_vector_type(4))) float  f32x4;

// ---- bf16 helpers (storage only; accumulation fp32) ----
__device__ __forceinline__ float bf2f(unsigned short u) {
    return __uint_as_float((unsigned int)u << 16);
}
__device__ __forceinline__ float2 bf2f2(ushort2 u) {
    return make_float2(bf2f(u.x), bf2f(u.y));
}
__device__ __forceinline__ unsigned short f2bf(float x) {
    unsigned int u = __float_as_uint(x);
    u += 0x7FFFu + ((u >> 16) & 1u);          // round-to-nearest-even
    return (unsigned short)(u >> 16);
}
__device__ __forceinline__ ushort2 f2bf2(float2 v) {
    return make_ushort2(f2bf(v.x), f2bf(v.y));
}

// ================= bucketed CSR build =================
// bucket = dst >> 8 (256 nodes/bucket). ebuf entry: x = src | dst_local<<17, y = 0.9*w.

__global__ __launch_bounds__(256) void k_hist(const int* __restrict__ dst,
                                              int* __restrict__ bucket_cnt) {
    __shared__ int hist[NB];
    int t = threadIdx.x;
    for (int b = t; b < NB; b += 256) hist[b] = 0;
    __syncthreads();
    int base = blockIdx.x * CHUNK;
    int end = min(base + CHUNK, N_EDGES);
    for (int i = base + t; i < end; i += 256)
        atomicAdd(&hist[dst[i] >> 8], 1);
    __syncthreads();
    for (int b = t; b < NB; b += 256)
        if (hist[b]) atomicAdd(&bucket_cnt[b], hist[b]);
}

__global__ __launch_bounds__(512) void k_scanb(const int* __restrict__ bucket_cnt,
                                               int* __restrict__ bucket_base,
                                               int* __restrict__ bucket_cursor) {
    __shared__ int s[512];
    int t = threadIdx.x;
    int v = (t < NB) ? bucket_cnt[t] : 0;
    s[t] = v;
    __syncthreads();
    for (int off = 1; off < 512; off <<= 1) {
        int u = (t >= off) ? s[t - off] : 0;
        __syncthreads();
        s[t] += u;
        __syncthreads();
    }
    if (t < NB) {
        int base = s[t] - v;
        bucket_base[t] = base;
        bucket_cursor[t] = base;
    }
    if (t == 0) bucket_base[NB] = N_EDGES;
}

__global__ __launch_bounds__(256) void k_part(const int* __restrict__ src,
                                              const int* __restrict__ dst,
                                              const float* __restrict__ ew,
                                              int* __restrict__ bucket_cursor,
                                              int2* __restrict__ ebuf) {
    __shared__ int lhist[NB], gbase[NB];
    int t = threadIdx.x;
    for (int b = t; b < NB; b += 256) lhist[b] = 0;
    __syncthreads();
    int base = blockIdx.x * CHUNK;
    int end = min(base + CHUNK, N_EDGES);
    for (int i = base + t; i < end; i += 256)
        atomicAdd(&lhist[dst[i] >> 8], 1);
    __syncthreads();
    for (int b = t; b < NB; b += 256) {
        int c = lhist[b];
        gbase[b] = c ? atomicAdd(&bucket_cursor[b], c) : 0;
        lhist[b] = 0;
    }
    __syncthreads();
    for (int i = base + t; i < end; i += 256) {
        int d = dst[i];
        int b = d >> 8;
        int r = atomicAdd(&lhist[b], 1);
        ebuf[gbase[b] + r] = make_int2(src[i] | ((d & 255) << 17),
                                       __float_as_int((1.0f - ALPHA) * ew[i]));
    }
}

// per-bucket degree via LDS counters (no global atomics)
__global__ __launch_bounds__(256) void k_deg(const int2* __restrict__ ebuf,
                                             const int* __restrict__ bucket_base,
                                             int* __restrict__ deg) {
    __shared__ int cnt[256];
    int t = threadIdx.x, b = blockIdx.x;
    cnt[t] = 0;
    __syncthreads();
    int beg = bucket_base[b], end = bucket_base[b + 1];
    for (int i = beg + t; i < end; i += 256)
        atomicAdd(&cnt[ebuf[i].x >> 17], 1);
    __syncthreads();
    int node = b * 256 + t;
    if (node < N_NODES) deg[node] = cnt[t];
}

__global__ __launch_bounds__(1024) void k_scan1(const int* __restrict__ deg,
                                                int* __restrict__ row_ptr,
                                                int* __restrict__ blocksum) {
    __shared__ int s[1024];
    int t = threadIdx.x;
    int i = blockIdx.x * 1024 + t;
    int v = (i < N_NODES) ? deg[i] : 0;
    s[t] = v;
    __syncthreads();
    for (int off = 1; off < 1024; off <<= 1) {
        int u = (t >= off) ? s[t - off] : 0;
        __syncthreads();
        s[t] += u;
        __syncthreads();
    }
    if (i < N_NODES) row_ptr[i] = s[t] - v;
    if (t == 1023) blocksum[blockIdx.x] = s[1023];
}

__global__ __launch_bounds__(128) void k_scan2(int* __restrict__ blocksum) {
    __shared__ int s[128];
    int t = threadIdx.x;
    int v = (t < SCAN_B) ? blocksum[t] : 0;
    s[t] = v;
    __syncthreads();
    for (int off = 1; off < 128; off <<= 1) {
        int u = (t >= off) ? s[t - off] : 0;
        __syncthreads();
        s[t] += u;
        __syncthreads();
    }
    if (t < SCAN_B) blocksum[t] = s[t] - v;
}

__global__ __launch_bounds__(1024) void k_scan3(int* __restrict__ row_ptr,
                                                const int* __restrict__ blocksum) {
    int t = threadIdx.x;
    int i = blockIdx.x * 1024 + t;
    if (i < N_NODES) row_ptr[i] += blocksum[blockIdx.x];
    if (i == 0) row_ptr[N_NODES] = N_EDGES;
}

// per-bucket counting-sort scatter; LDS cursors, colw writes confined to ~32KB
__global__ __launch_bounds__(256) void k_scatter2(const int2* __restrict__ ebuf,
                                                  const int* __restrict__ bucket_base,
                                                  const int* __restrict__ row_ptr,
                                                  int2* __restrict__ colw) {
    __shared__ int lcur[256];
    int t = threadIdx.x, b = blockIdx.x;
    int node = b * 256 + t;
    lcur[t] = (node < N_NODES) ? row_ptr[node] : 0;
    __syncthreads();
    int beg = bucket_base[b], end = bucket_base[b + 1];
    for (int i = beg + t; i < end; i += 256) {
        int2 e = ebuf[i];
        int pos = atomicAdd(&lcur[e.x >> 17], 1);
        colw[pos] = make_int2(e.x & 0x1FFFF, e.y);
    }
}

// ===== weight pack: fp32 -> bf16 B-fragment order =====
// frag idx = ((nt*4 + ch)*64 + lane)*8 + j ;
// value = W[ch*32 + (lane>>4)*8 + j][nt*16 + (lane&15)]
// layers at wp[l*16384] (l=0..3), w_out at wp[65536] (nt 0..3), w_in at wp[73728].
__global__ void k_prepw(const float* __restrict__ gcnw, const float* __restrict__ wout,
                        const float* __restrict__ win, unsigned short* __restrict__ wp) {
    int tid = blockIdx.x * 256 + threadIdx.x;
    if (tid < 65536) {
        int l = tid >> 14;
        int r = tid & 16383;
        int j = r & 7, lane = (r >> 3) & 63, ch = (r >> 9) & 3, nt = r >> 11;
        int n = nt * 16 + (lane & 15);
        int k = ch * 32 + (lane >> 4) * 8 + j;
        wp[tid] = f2bf(gcnw[l * 16384 + k * 128 + n]);
    } else if (tid < 73728) {
        int r = tid - 65536;
        int j = r & 7, lane = (r >> 3) & 63, ch = (r >> 9) & 3, nt = r >> 11; // nt 0..3
        int n = nt * 16 + (lane & 15);
        int k = ch * 32 + (lane >> 4) * 8 + j;
        wp[tid] = f2bf(wout[k * 64 + n]);
    } else if (tid < 90112) {
        int r = tid - 73728;
        int j = r & 7, lane = (r >> 3) & 63, ch = (r >> 9) & 3, nt = r >> 11; // nt 0..7
        int n = nt * 16 + (lane & 15);
        int k = ch * 32 + (lane >> 4) * 8 + j;
        wp[tid] = f2bf(win[k * 128 + n]);
    }
}

// ===== SpMM gather (bf16 rows): hi[i] = ALPHA*h0[i] + sum_e w*h[src] =====
__global__ __launch_bounds__(256, 8) void k_spmm_csr(
    const int* __restrict__ row_ptr, const int2* __restrict__ colw,
    const unsigned short* __restrict__ h, const unsigned short* __restrict__ h0,
    unsigned short* __restrict__ out) {
    int node = blockIdx.x * 4 + (threadIdx.x >> 6);
    if (node >= N_NODES) return;
    int lane = threadIdx.x & 63;
    int beg = row_ptr[node], end = row_ptr[node + 1];

    float2 z = bf2f2(((const ushort2*)(h0 + (size_t)node * DIM))[lane]);
    float2 acc = make_float2(ALPHA * z.x, ALPHA * z.y);

    int e = beg;
    for (; e + 3 < end; e += 4) {
        int2 c0 = colw[e];
        int2 c1 = colw[e + 1];
        int2 c2 = colw[e + 2];
        int2 c3 = colw[e + 3];
        float2 v0 = bf2f2(((const ushort2*)(h + (size_t)c0.x * DIM))[lane]);
        float2 v1 = bf2f2(((const ushort2*)(h + (size_t)c1.x * DIM))[lane]);
        float2 v2 = bf2f2(((const ushort2*)(h + (size_t)c2.x * DIM))[lane]);
        float2 v3 = bf2f2(((const ushort2*)(h + (size_t)c3.x * DIM))[lane]);
        float w0 = __int_as_float(c0.y), w1 = __int_as_float(c1.y);
        float w2 = __int_as_float(c2.y), w3 = __int_as_float(c3.y);
        acc.x += w0 * v0.x + w1 * v1.x + w2 * v2.x + w3 * v3.x;
        acc.y += w0 * v0.y + w1 * v1.y + w2 * v2.y + w3 * v3.y;
    }
    for (; e < end; e++) {
        int2 c0 = colw[e];
        float2 v0 = bf2f2(((const ushort2*)(h + (size_t)c0.x * DIM))[lane]);
        float w0 = __int_as_float(c0.y);
        acc.x += w0 * v0.x;
        acc.y += w0 * v0.y;
    }
    ((ushort2*)(out + (size_t)node * DIM))[lane] = f2bf2(acc);
}

// ===== MFMA input GEMM: h0 = relu(x @ W_in + b)  (x fp32 -> bf16 in-reg) =====
__global__ __launch_bounds__(256) void k_in_mfma(
    const float* __restrict__ x, const unsigned short* __restrict__ wp,
    const float* __restrict__ b_in, unsigned short* __restrict__ h0) {
    int wave = threadIdx.x >> 6, lane = threadIdx.x & 63;
    int stripe = blockIdx.x * 4 + wave;
    if (stripe >= STRIPES) return;
    int r0 = stripe * 16;
    int m = lane & 15, q = lane >> 4;

    f32x4 acc[8];
    #pragma unroll
    for (int nt = 0; nt < 8; nt++) acc[nt] = (f32x4){0.f, 0.f, 0.f, 0.f};

    const float* xr = x + (size_t)(r0 + m) * DIM + q * 8;
    #pragma unroll
    for (int ch = 0; ch < 4; ch++) {
        float4 a0 = *(const float4*)(xr + ch * 32);
        float4 a1 = *(const float4*)(xr + ch * 32 + 4);
        bf16x8 a;
        a[0] = (short)f2bf(a0.x); a[1] = (short)f2bf(a0.y);
        a[2] = (short)f2bf(a0.z); a[3] = (short)f2bf(a0.w);
        a[4] = (short)f2bf(a1.x); a[5] = (short)f2bf(a1.y);
        a[6] = (short)f2bf(a1.z); a[7] = (short)f2bf(a1.w);
        #pragma unroll
        for (int nt = 0; nt < 8; nt++) {
            bf16x8 b = *(const bf16x8*)(wp + (((nt * 4 + ch) * 64 + lane) << 3));
            acc[nt] = __builtin_amdgcn_mfma_f32_16x16x32_bf16(a, b, acc[nt], 0, 0, 0);
        }
    }

    #pragma unroll
    for (int nt = 0; nt < 8; nt++) {
        int col = nt * 16 + m;
        float bias = b_in[col];
        #pragma unroll
        for (int r = 0; r < 4; r++) {
            int row = r0 + q * 4 + r;
            h0[(size_t)row * DIM + col] = f2bf(fmaxf(acc[nt][r] + bias, 0.f));
        }
    }
}

// ===== MFMA layer GEMM: h = relu(theta*(s@W) + (1-theta)*s + hprev) =====
__global__ __launch_bounds__(256) void k_layer_mfma(
    const unsigned short* __restrict__ s_in, const unsigned short* __restrict__ hprev,
    const unsigned short* __restrict__ wp, unsigned short* __restrict__ hout,
    float theta) {
    int wave = threadIdx.x >> 6, lane = threadIdx.x & 63;
    int stripe = blockIdx.x * 4 + wave;
    if (stripe >= STRIPES) return;
    int r0 = stripe * 16;
    int m = lane & 15, q = lane >> 4;
    float omt = 1.f - theta;

    f32x4 acc[8];
    #pragma unroll
    for (int nt = 0; nt < 8; nt++) acc[nt] = (f32x4){0.f, 0.f, 0.f, 0.f};

    const unsigned short* arow = s_in + (size_t)(r0 + m) * DIM + q * 8;
    #pragma unroll
    for (int ch = 0; ch < 4; ch++) {
        bf16x8 a = *(const bf16x8*)(arow + ch * 32);
        #pragma unroll
        for (int nt = 0; nt < 8; nt++) {
            bf16x8 b = *(const bf16x8*)(wp + (((nt * 4 + ch) * 64 + lane) << 3));
            acc[nt] = __builtin_amdgcn_mfma_f32_16x16x32_bf16(a, b, acc[nt], 0, 0, 0);
        }
    }

    #pragma unroll
    for (int nt = 0; nt < 8; nt++) {
        int col = nt * 16 + m;
        #pragma unroll
        for (int r = 0; r < 4; r++) {
            int row = r0 + q * 4 + r;
            size_t idx = (size_t)row * DIM + col;
            float sup = bf2f(s_in[idx]);
            float hp  = bf2f(hprev[idx]);
            float o = theta * acc[nt][r] + omt * sup + hp;
            hout[idx] = f2bf(fmaxf(o, 0.f));
        }
    }
}

// ===== MFMA output GEMM + log_softmax =====
__global__ __launch_bounds__(256) void k_out_mfma(
    const unsigned short* __restrict__ h, const unsigned short* __restrict__ wp,
    const float* __restrict__ bo, float* __restrict__ out) {
    int wave = threadIdx.x >> 6, lane = threadIdx.x & 63;
    int stripe = blockIdx.x * 4 + wave;
    if (stripe >= STRIPES) return;
    int r0 = stripe * 16;
    int m = lane & 15, q = lane >> 4;

    f32x4 acc[4];
    #pragma unroll
    for (int nt = 0; nt < 4; nt++) acc[nt] = (f32x4){0.f, 0.f, 0.f, 0.f};

    const unsigned short* arow = h + (size_t)(r0 + m) * DIM + q * 8;
    #pragma unroll
    for (int ch = 0; ch < 4; ch++) {
        bf16x8 a = *(const bf16x8*)(arow + ch * 32);
        #pragma unroll
        for (int nt = 0; nt < 4; nt++) {
            bf16x8 b = *(const bf16x8*)(wp + (((nt * 4 + ch) * 64 + lane) << 3));
            acc[nt] = __builtin_amdgcn_mfma_f32_16x16x32_bf16(a, b, acc[nt], 0, 0, 0);
        }
    }

    float v[4][4];
    #pragma unroll
    for (int nt = 0; nt < 4; nt++) {
        float bias = bo[nt * 16 + m];
        #pragma unroll
        for (int r = 0; r < 4; r++) v[nt][r] = acc[nt][r] + bias;
    }
    #pragma unroll
    for (int r = 0; r < 4; r++) {
        float mx = fmaxf(fmaxf(v[0][r], v[1][r]), fmaxf(v[2][r], v[3][r]));
        #pragma unroll
        for (int off = 1; off < 16; off <<= 1) mx = fmaxf(mx, __shfl_xor(mx, off));
        float s = 0.f;
        #pragma unroll
        for (int nt = 0; nt < 4; nt++) s += __expf(v[nt][r] - mx);
        #pragma unroll
        for (int off = 1; off < 16; off <<= 1) s += __shfl_xor(s, off);
        float lse = mx + logf(s);
        int row = r0 + q * 4 + r;
        #pragma unroll
        for (int nt = 0; nt < 4; nt++)
            out[(size_t)row * NCLS + nt * 16 + m] = v[nt][r] - lse;
    }
}

extern "C" void kernel_launch(void* const* d_in, const int* in_sizes, int n_in,
                              void* d_out, int out_size, void* d_ws, size_t ws_size,
                              hipStream_t stream) {
    const float* x    = (const float*)d_in[0];
    const int*   esrc = (const int*)d_in[1];
    const int*   edst = (const int*)d_in[2];
    const float* ew   = (const float*)d_in[3];
    const float* w_in = (const float*)d_in[4];
    const float* b_in = (const float*)d_in[5];
    const float* gcnw = (const float*)d_in[6];   // [4,128,128]
    const float* wout = (const float*)d_in[7];
    const float* bout = (const float*)d_in[8];
    float* out = (float*)d_out;

    // workspace layout
    unsigned short* h0 = (unsigned short*)d_ws;        // NF ushorts each
    unsigned short* hA = h0 + NF;
    unsigned short* hB = hA + NF;
    unsigned short* hi = hB + NF;
    unsigned short* wp = hi + NF;                      // 90112 ushorts packed W
    int2* colw = (int2*)(wp + 90112);                  // E int2
    int2* ebuf = colw + N_EDGES;                       // E int2 (bucket-grouped)
    int*  row_ptr       = (int*)(ebuf + N_EDGES);      // N+1
    int*  deg           = row_ptr + (N_NODES + 1);     // N
    int*  blocksum      = deg + N_NODES;               // SCAN_B
    int*  bucket_cnt    = blocksum + SCAN_B;           // NB
    int*  bucket_base   = bucket_cnt + NB;             // NB+1
    int*  bucket_cursor = bucket_base + (NB + 1);      // NB

    const int PART_B = (N_EDGES + CHUNK - 1) / CHUNK;  // 782
    const int MFMA_BLOCKS = (STRIPES + 3) / 4;

    // ---- weight pack ----
    k_prepw<<<(90112 + 255) / 256, 256, 0, stream>>>(gcnw, wout, w_in, wp);

    // ---- bucketed CSR build ----
    hipMemsetAsync(bucket_cnt, 0, NB * sizeof(int), stream);
    k_hist<<<PART_B, 256, 0, stream>>>(edst, bucket_cnt);
    k_scanb<<<1, 512, 0, stream>>>(bucket_cnt, bucket_base, bucket_cursor);
    k_part<<<PART_B, 256, 0, stream>>>(esrc, edst, ew, bucket_cursor, ebuf);
    k_deg<<<NB, 256, 0, stream>>>(ebuf, bucket_base, deg);
    k_scan1<<<SCAN_B, 1024, 0, stream>>>(deg, row_ptr, blocksum);
    k_scan2<<<1, 128, 0, stream>>>(blocksum);
    k_scan3<<<SCAN_B, 1024, 0, stream>>>(row_ptr, blocksum);
    k_scatter2<<<NB, 256, 0, stream>>>(ebuf, bucket_base, row_ptr, colw);

    // h0 = relu(x @ w_in + b_in)
    k_in_mfma<<<MFMA_BLOCKS, 256, 0, stream>>>(x, wp + 73728, b_in, h0);

    const unsigned short* hprev = h0;
    unsigned short* bufs[2] = {hA, hB};
    for (int l = 0; l < 4; l++) {
        float theta = logf(0.5f / (float)(l + 2) + 1.0f);
        k_spmm_csr<<<(N_NODES + 3) / 4, 256, 0, stream>>>(row_ptr, colw, hprev, h0, hi);
        unsigned short* hnew = bufs[l & 1];
        k_layer_mfma<<<MFMA_BLOCKS, 256, 0, stream>>>(hi, hprev, wp + (size_t)l * 16384,
                                                      hnew, theta);
        hprev = hnew;
    }

    // out = log_softmax(h @ w_out + b_out)
    k_out_mfma<<<MFMA_BLOCKS, 256, 0, stream>>>(hprev, wp + 65536, bout, out);
}